// Round 1
// baseline (388.574 us; speedup 1.0000x reference)
//
#include <hip/hip_runtime.h>

typedef __attribute__((ext_vector_type(8))) short bf16x8;
typedef __attribute__((ext_vector_type(4))) float f32x4;

#define N_TOK 4096

static __device__ __forceinline__ ushort f2bf(float f) {
    union { float f; unsigned u; } x; x.f = f;
    unsigned u = x.u;
    unsigned r = (u + 0x7FFFu + ((u >> 16) & 1u)) >> 16;
    return (ushort)r;
}

// ---------------- cast x -> bf16 ----------------
__global__ void cast_f32_bf16(const float* __restrict__ src, ushort* __restrict__ dst, int n4) {
    int i = blockIdx.x * blockDim.x + threadIdx.x;
    if (i >= n4) return;
    float4 v = ((const float4*)src)[i];
    ushort4 o;
    o.x = f2bf(v.x); o.y = f2bf(v.y); o.z = f2bf(v.z); o.w = f2bf(v.w);
    ((ushort4*)dst)[i] = o;
}

// ---------------- transpose weight [R,C] -> bf16 [C,R], batched in grid.y ----
__global__ void transpose_f32_bf16(const float* __restrict__ src, ushort* __restrict__ dst,
                                   int R, int C) {
    int idx = blockIdx.x * blockDim.x + threadIdx.x;
    int total = R * C;
    long boff = (long)blockIdx.y * total;
    if (idx >= total) return;
    int r = idx / C, c = idx % C;
    dst[boff + (long)c * R + r] = f2bf(src[boff + idx]);
}

// ---------------- rpe 5-plane weighted reduce -> bf16 [N,N] ----------------
__global__ void rpe_reduce(const float* __restrict__ rpe, const float* __restrict__ rpe_w,
                           const float* __restrict__ rpe_b, ushort* __restrict__ out) {
    const long QUADS = (long)N_TOK * N_TOK / 4;
    float w0 = rpe_w[0], w1 = rpe_w[1], w2 = rpe_w[2], w3 = rpe_w[3], w4 = rpe_w[4];
    float bb = rpe_b[0];
    const float4* p = (const float4*)rpe;
    for (long i = blockIdx.x * (long)blockDim.x + threadIdx.x; i < QUADS;
         i += (long)gridDim.x * blockDim.x) {
        float4 a0 = p[i];
        float4 a1 = p[i + QUADS];
        float4 a2 = p[i + 2 * QUADS];
        float4 a3 = p[i + 3 * QUADS];
        float4 a4 = p[i + 4 * QUADS];
        ushort4 o;
        o.x = f2bf(bb + w0 * a0.x + w1 * a1.x + w2 * a2.x + w3 * a3.x + w4 * a4.x);
        o.y = f2bf(bb + w0 * a0.y + w1 * a1.y + w2 * a2.y + w3 * a3.y + w4 * a4.y);
        o.z = f2bf(bb + w0 * a0.z + w1 * a1.z + w2 * a2.z + w3 * a3.z + w4 * a4.z);
        o.w = f2bf(bb + w0 * a0.w + w1 * a1.w + w2 * a2.w + w3 * a3.w + w4 * a4.w);
        ((ushort4*)out)[i] = o;
    }
}

// ---------------- QKV projection: relu(xb @ W^T + b) ----------------
// grid: (N/64, 12); blockIdx.y: h = y&3, which = y>>2 (0=q,1=k,2=v)
__global__ __launch_bounds__(256) void qkv_proj(
    const ushort* __restrict__ xb, const ushort* __restrict__ WqT,
    const ushort* __restrict__ WkT, const ushort* __restrict__ WvT,
    const float* __restrict__ bq, const float* __restrict__ bk, const float* __restrict__ bv,
    ushort* __restrict__ qb, ushort* __restrict__ kb, ushort* __restrict__ vT) {
    int m0 = blockIdx.x * 64;
    int h = blockIdx.y & 3, which = blockIdx.y >> 2;
    int wave = threadIdx.x >> 6, lane = threadIdx.x & 63;
    int fr = lane & 15, kg = lane >> 4;
    int wm = m0 + wave * 16;
    const ushort* WT = (which == 0 ? WqT : which == 1 ? WkT : WvT) + (long)h * 64 * 128;
    const float* bias = (which == 0 ? bq : which == 1 ? bk : bv) + h * 64;
    f32x4 acc[4] = {};
    for (int k0 = 0; k0 < 128; k0 += 32) {
        bf16x8 a = *(const bf16x8*)(xb + (long)(wm + fr) * 128 + k0 + kg * 8);
#pragma unroll
        for (int t = 0; t < 4; ++t) {
            bf16x8 b = *(const bf16x8*)(WT + (long)(t * 16 + fr) * 128 + k0 + kg * 8);
            acc[t] = __builtin_amdgcn_mfma_f32_16x16x32_bf16(a, b, acc[t], 0, 0, 0);
        }
    }
    int rb = wm + kg * 4;
#pragma unroll
    for (int t = 0; t < 4; ++t) {
        int col = t * 16 + fr;
        float bs = bias[col];
        if (which == 2) {
            ushort4 o;
            o.x = f2bf(fmaxf(acc[t][0] + bs, 0.f));
            o.y = f2bf(fmaxf(acc[t][1] + bs, 0.f));
            o.z = f2bf(fmaxf(acc[t][2] + bs, 0.f));
            o.w = f2bf(fmaxf(acc[t][3] + bs, 0.f));
            *(ushort4*)(vT + ((long)h * 64 + col) * N_TOK + rb) = o;
        } else {
            ushort* dst = (which == 0 ? qb : kb) + (long)h * N_TOK * 64;
#pragma unroll
            for (int r = 0; r < 4; ++r)
                dst[(long)(rb + r) * 64 + col] = f2bf(fmaxf(acc[t][r] + bs, 0.f));
        }
    }
}

// ---------------- flash attention: 1 wave = 16 q-rows, writes mho^T ---------
__global__ __launch_bounds__(64) void attn_flash(
    const ushort* __restrict__ qb, const ushort* __restrict__ kb,
    const ushort* __restrict__ vT, ushort* __restrict__ mhoT) {
    int h = blockIdx.y;
    int q0 = blockIdx.x * 16;
    int lane = threadIdx.x;
    int fr = lane & 15, kg = lane >> 4;
    const ushort* qh = qb + (long)h * N_TOK * 64;
    const ushort* kh = kb + (long)h * N_TOK * 64;
    const ushort* vh = vT + (long)h * 64 * N_TOK;
    bf16x8 qf0 = *(const bf16x8*)(qh + (long)(q0 + fr) * 64 + kg * 8);
    bf16x8 qf1 = *(const bf16x8*)(qh + (long)(q0 + fr) * 64 + 32 + kg * 8);
    f32x4 o0 = {}, o1 = {}, o2 = {}, o3 = {};
    float mrun[4], lrun[4];
#pragma unroll
    for (int r = 0; r < 4; ++r) { mrun[r] = -1e30f; lrun[r] = 0.f; }
    __shared__ ushort plds[16 * 32];
    for (int n0 = 0; n0 < N_TOK; n0 += 32) {
        f32x4 s0 = {}, s1 = {};
        {
            const ushort* kr = kh + (long)(n0 + fr) * 64 + kg * 8;
            bf16x8 ka = *(const bf16x8*)(kr);
            bf16x8 kb8 = *(const bf16x8*)(kr + 32);
            s0 = __builtin_amdgcn_mfma_f32_16x16x32_bf16(qf0, ka, s0, 0, 0, 0);
            s0 = __builtin_amdgcn_mfma_f32_16x16x32_bf16(qf1, kb8, s0, 0, 0, 0);
        }
        {
            const ushort* kr = kh + (long)(n0 + 16 + fr) * 64 + kg * 8;
            bf16x8 ka = *(const bf16x8*)(kr);
            bf16x8 kb8 = *(const bf16x8*)(kr + 32);
            s1 = __builtin_amdgcn_mfma_f32_16x16x32_bf16(qf0, ka, s1, 0, 0, 0);
            s1 = __builtin_amdgcn_mfma_f32_16x16x32_bf16(qf1, kb8, s1, 0, 0, 0);
        }
        float p0[4], p1[4], alpha[4];
#pragma unroll
        for (int r = 0; r < 4; ++r) {
            float a0 = s0[r] * 0.125f, a1 = s1[r] * 0.125f;
            float mx = fmaxf(a0, a1);
#pragma unroll
            for (int off = 1; off < 16; off <<= 1) mx = fmaxf(mx, __shfl_xor(mx, off));
            float mnew = fmaxf(mrun[r], mx);
            alpha[r] = __expf(mrun[r] - mnew);
            p0[r] = __expf(a0 - mnew);
            p1[r] = __expf(a1 - mnew);
            float rs = p0[r] + p1[r];
#pragma unroll
            for (int off = 1; off < 16; off <<= 1) rs += __shfl_xor(rs, off);
            lrun[r] = lrun[r] * alpha[r] + rs;
            mrun[r] = mnew;
        }
#pragma unroll
        for (int r = 0; r < 4; ++r) {
            o0[r] *= alpha[r]; o1[r] *= alpha[r]; o2[r] *= alpha[r]; o3[r] *= alpha[r];
        }
#pragma unroll
        for (int r = 0; r < 4; ++r) {
            plds[(kg * 4 + r) * 32 + fr] = f2bf(p0[r]);
            plds[(kg * 4 + r) * 32 + 16 + fr] = f2bf(p1[r]);
        }
        bf16x8 pf = *(const bf16x8*)(plds + fr * 32 + kg * 8);
        const ushort* vr = vh + n0 + kg * 8;
        bf16x8 v0 = *(const bf16x8*)(vr + (long)(0 + fr) * N_TOK);
        bf16x8 v1 = *(const bf16x8*)(vr + (long)(16 + fr) * N_TOK);
        bf16x8 v2 = *(const bf16x8*)(vr + (long)(32 + fr) * N_TOK);
        bf16x8 v3 = *(const bf16x8*)(vr + (long)(48 + fr) * N_TOK);
        o0 = __builtin_amdgcn_mfma_f32_16x16x32_bf16(pf, v0, o0, 0, 0, 0);
        o1 = __builtin_amdgcn_mfma_f32_16x16x32_bf16(pf, v1, o1, 0, 0, 0);
        o2 = __builtin_amdgcn_mfma_f32_16x16x32_bf16(pf, v2, o2, 0, 0, 0);
        o3 = __builtin_amdgcn_mfma_f32_16x16x32_bf16(pf, v3, o3, 0, 0, 0);
    }
#pragma unroll
    for (int r = 0; r < 4; ++r) lrun[r] = 1.0f / lrun[r];
    f32x4 os[4] = {o0, o1, o2, o3};
#pragma unroll
    for (int t = 0; t < 4; ++t) {
        ushort4 st;
        st.x = f2bf(os[t][0] * lrun[0]);
        st.y = f2bf(os[t][1] * lrun[1]);
        st.z = f2bf(os[t][2] * lrun[2]);
        st.w = f2bf(os[t][3] * lrun[3]);
        *(ushort4*)(mhoT + ((long)h * 64 + t * 16 + fr) * N_TOK + q0 + kg * 4) = st;
    }
}

// ---------------- generic gemm_bt: C = act(A @ BT^T + bias [+ res]) ---------
// OUT_MODE 0: bf16 row-major out; OUT_MODE 1: fp32 out = v + res
template <int RELU, int OUT_MODE>
__global__ __launch_bounds__(256) void gemm_bt(
    const ushort* __restrict__ A, const ushort* __restrict__ BT,
    const float* __restrict__ bias, void* __restrict__ outp,
    const float* __restrict__ res, int Ncols, int Kd) {
    int m0 = blockIdx.x * 64, n0 = blockIdx.y * 64;
    int wave = threadIdx.x >> 6, lane = threadIdx.x & 63;
    int fr = lane & 15, kg = lane >> 4;
    int wm = m0 + wave * 16;
    f32x4 acc[4] = {};
    for (int k0 = 0; k0 < Kd; k0 += 32) {
        bf16x8 a = *(const bf16x8*)(A + (long)(wm + fr) * Kd + k0 + kg * 8);
#pragma unroll
        for (int t = 0; t < 4; ++t) {
            bf16x8 b = *(const bf16x8*)(BT + (long)(n0 + t * 16 + fr) * Kd + k0 + kg * 8);
            acc[t] = __builtin_amdgcn_mfma_f32_16x16x32_bf16(a, b, acc[t], 0, 0, 0);
        }
    }
    int rb = wm + kg * 4;
#pragma unroll
    for (int t = 0; t < 4; ++t) {
        int col = n0 + t * 16 + fr;
        float bs = bias ? bias[col] : 0.f;
#pragma unroll
        for (int r = 0; r < 4; ++r) {
            float v = acc[t][r] + bs;
            if (RELU) v = fmaxf(v, 0.f);
            long off = (long)(rb + r) * Ncols + col;
            if (OUT_MODE == 0) ((ushort*)outp)[off] = f2bf(v);
            else ((float*)outp)[off] = v + res[off];
        }
    }
}

// ---------------- layernorm over D=128, 1 wave per row ----------------
template <int WF, int WB>
__global__ __launch_bounds__(64) void layer_norm_k(
    const float* __restrict__ src, const float* __restrict__ g, const float* __restrict__ b,
    float* __restrict__ dstf, ushort* __restrict__ dstb) {
    int row = blockIdx.x, lane = threadIdx.x;
    float2 v = *(const float2*)(src + (long)row * 128 + lane * 2);
    float s = v.x + v.y;
#pragma unroll
    for (int off = 32; off >= 1; off >>= 1) s += __shfl_xor(s, off);
    float mean = s * (1.0f / 128.0f);
    float d0 = v.x - mean, d1 = v.y - mean;
    float ss = d0 * d0 + d1 * d1;
#pragma unroll
    for (int off = 32; off >= 1; off >>= 1) ss += __shfl_xor(ss, off);
    float rstd = rsqrtf(ss * (1.0f / 128.0f) + 1e-5f);
    float y0 = d0 * rstd * g[lane * 2] + b[lane * 2];
    float y1 = d1 * rstd * g[lane * 2 + 1] + b[lane * 2 + 1];
    if (WF) {
        float2 o; o.x = y0; o.y = y1;
        *(float2*)(dstf + (long)row * 128 + lane * 2) = o;
    }
    if (WB) {
        ushort2 o; o.x = f2bf(y0); o.y = f2bf(y1);
        *(ushort2*)(dstb + (long)row * 128 + lane * 2) = o;
    }
}

extern "C" void kernel_launch(void* const* d_in, const int* in_sizes, int n_in,
                              void* d_out, int out_size, void* d_ws, size_t ws_size,
                              hipStream_t stream) {
    const float* x     = (const float*)d_in[0];
    const float* rpe   = (const float*)d_in[1];
    const float* Wq    = (const float*)d_in[2];
    const float* bq    = (const float*)d_in[3];
    const float* Wk    = (const float*)d_in[4];
    const float* bk    = (const float*)d_in[5];
    const float* Wv    = (const float*)d_in[6];
    const float* bv    = (const float*)d_in[7];
    const float* rpe_w = (const float*)d_in[8];
    const float* rpe_b = (const float*)d_in[9];
    const float* Wo    = (const float*)d_in[10];
    const float* bo    = (const float*)d_in[11];
    const float* W1    = (const float*)d_in[12];
    const float* b1    = (const float*)d_in[13];
    const float* W2    = (const float*)d_in[14];
    const float* b2    = (const float*)d_in[15];
    const float* g1    = (const float*)d_in[16];
    const float* lb1   = (const float*)d_in[17];
    const float* g2    = (const float*)d_in[18];
    const float* lb2   = (const float*)d_in[19];

    char* wp = (char*)d_ws;
    auto alloc = [&](size_t sz) { char* p = wp; wp += (sz + 255) & ~(size_t)255; return p; };
    ushort* xb   = (ushort*)alloc((size_t)4096 * 128 * 2);
    ushort* WqT  = (ushort*)alloc((size_t)4 * 64 * 128 * 2);
    ushort* WkT  = (ushort*)alloc((size_t)4 * 64 * 128 * 2);
    ushort* WvT  = (ushort*)alloc((size_t)4 * 64 * 128 * 2);
    ushort* WoT  = (ushort*)alloc((size_t)128 * 256 * 2);
    ushort* W1T  = (ushort*)alloc((size_t)256 * 128 * 2);
    ushort* W2T  = (ushort*)alloc((size_t)128 * 256 * 2);
    ushort* qb   = (ushort*)alloc((size_t)4 * 4096 * 64 * 2);
    ushort* kbuf = (ushort*)alloc((size_t)4 * 4096 * 64 * 2);
    ushort* vT   = (ushort*)alloc((size_t)4 * 64 * 4096 * 2);
    ushort* rpeW = (ushort*)alloc((size_t)4096 * 4096 * 2);
    ushort* mhoT = (ushort*)alloc((size_t)256 * 4096 * 2);
    ushort* adj  = (ushort*)alloc((size_t)4096 * 256 * 2);
    float*  res1 = (float*)alloc((size_t)4096 * 128 * 4);
    float*  x1f  = (float*)alloc((size_t)4096 * 128 * 4);
    ushort* x1b  = (ushort*)alloc((size_t)4096 * 128 * 2);
    ushort* h1   = (ushort*)alloc((size_t)4096 * 256 * 2);
    float*  res2 = (float*)alloc((size_t)4096 * 128 * 4);

    cast_f32_bf16<<<512, 256, 0, stream>>>(x, xb, 4096 * 128 / 4);
    transpose_f32_bf16<<<dim3(32, 4), 256, 0, stream>>>(Wq, WqT, 128, 64);
    transpose_f32_bf16<<<dim3(32, 4), 256, 0, stream>>>(Wk, WkT, 128, 64);
    transpose_f32_bf16<<<dim3(32, 4), 256, 0, stream>>>(Wv, WvT, 128, 64);
    transpose_f32_bf16<<<dim3(128, 1), 256, 0, stream>>>(Wo, WoT, 256, 128);
    transpose_f32_bf16<<<dim3(128, 1), 256, 0, stream>>>(W1, W1T, 128, 256);
    transpose_f32_bf16<<<dim3(128, 1), 256, 0, stream>>>(W2, W2T, 256, 128);
    rpe_reduce<<<2048, 256, 0, stream>>>(rpe, rpe_w, rpe_b, rpeW);
    qkv_proj<<<dim3(64, 12), 256, 0, stream>>>(xb, WqT, WkT, WvT, bq, bk, bv, qb, kbuf, vT);
    attn_flash<<<dim3(256, 4), 64, 0, stream>>>(qb, kbuf, vT, mhoT);
    gemm_bt<0, 0><<<dim3(64, 4), 256, 0, stream>>>(rpeW, mhoT, nullptr, adj, nullptr, 256, 4096);
    gemm_bt<0, 1><<<dim3(64, 2), 256, 0, stream>>>(adj, WoT, bo, res1, x, 128, 256);
    layer_norm_k<1, 1><<<4096, 64, 0, stream>>>(res1, g1, lb1, x1f, x1b);
    gemm_bt<1, 0><<<dim3(64, 4), 256, 0, stream>>>(x1b, W1T, b1, h1, nullptr, 256, 128);
    gemm_bt<0, 1><<<dim3(64, 2), 256, 0, stream>>>(h1, W2T, b2, res2, x1f, 128, 256);
    layer_norm_k<1, 0><<<4096, 64, 0, stream>>>(res2, g2, lb2, (float*)d_out, nullptr);
}

// Round 3
// 237.389 us; speedup vs baseline: 1.6369x; 1.6369x over previous
//
#include <hip/hip_runtime.h>

typedef __attribute__((ext_vector_type(8))) short bf16x8;
typedef __attribute__((ext_vector_type(4))) float f32x4;

#define N_TOK 4096
#define NC_ATT 4
#define NC_GEMM 4

static __device__ __forceinline__ ushort f2bf(float f) {
    union { float f; unsigned u; } x; x.f = f;
    unsigned u = x.u;
    unsigned r = (u + 0x7FFFu + ((u >> 16) & 1u)) >> 16;
    return (ushort)r;
}

// ---------------- cast x -> bf16 ----------------
__global__ void cast_f32_bf16(const float* __restrict__ src, ushort* __restrict__ dst, int n4) {
    int i = blockIdx.x * blockDim.x + threadIdx.x;
    if (i >= n4) return;
    float4 v = ((const float4*)src)[i];
    ushort4 o;
    o.x = f2bf(v.x); o.y = f2bf(v.y); o.z = f2bf(v.z); o.w = f2bf(v.w);
    ((ushort4*)dst)[i] = o;
}

// ---------------- transpose weight [R,C] -> bf16 [C,R], batched in grid.y ----
__global__ void transpose_f32_bf16(const float* __restrict__ src, ushort* __restrict__ dst,
                                   int R, int C) {
    int idx = blockIdx.x * blockDim.x + threadIdx.x;
    int total = R * C;
    long boff = (long)blockIdx.y * total;
    if (idx >= total) return;
    int r = idx / C, c = idx % C;
    dst[boff + (long)c * R + r] = f2bf(src[boff + idx]);
}

// ---------------- rpe 5-plane weighted reduce -> bf16 [N,N] ----------------
__global__ void rpe_reduce(const float* __restrict__ rpe, const float* __restrict__ rpe_w,
                           const float* __restrict__ rpe_b, ushort* __restrict__ out) {
    const long QUADS = (long)N_TOK * N_TOK / 4;
    float w0 = rpe_w[0], w1 = rpe_w[1], w2 = rpe_w[2], w3 = rpe_w[3], w4 = rpe_w[4];
    float bb = rpe_b[0];
    const float4* p = (const float4*)rpe;
    for (long i = blockIdx.x * (long)blockDim.x + threadIdx.x; i < QUADS;
         i += (long)gridDim.x * blockDim.x) {
        float4 a0 = p[i];
        float4 a1 = p[i + QUADS];
        float4 a2 = p[i + 2 * QUADS];
        float4 a3 = p[i + 3 * QUADS];
        float4 a4 = p[i + 4 * QUADS];
        ushort4 o;
        o.x = f2bf(bb + w0 * a0.x + w1 * a1.x + w2 * a2.x + w3 * a3.x + w4 * a4.x);
        o.y = f2bf(bb + w0 * a0.y + w1 * a1.y + w2 * a2.y + w3 * a3.y + w4 * a4.y);
        o.z = f2bf(bb + w0 * a0.z + w1 * a1.z + w2 * a2.z + w3 * a3.z + w4 * a4.z);
        o.w = f2bf(bb + w0 * a0.w + w1 * a1.w + w2 * a2.w + w3 * a3.w + w4 * a4.w);
        ((ushort4*)out)[i] = o;
    }
}

// ---------------- QKV projection: relu(xb @ W^T + b), q pre-scaled 0.125 ----
__global__ __launch_bounds__(256) void qkv_proj(
    const ushort* __restrict__ xb, const ushort* __restrict__ WqT,
    const ushort* __restrict__ WkT, const ushort* __restrict__ WvT,
    const float* __restrict__ bq, const float* __restrict__ bk, const float* __restrict__ bv,
    ushort* __restrict__ qb, ushort* __restrict__ kb, ushort* __restrict__ vT) {
    int m0 = blockIdx.x * 64;
    int h = blockIdx.y & 3, which = blockIdx.y >> 2;
    int wave = threadIdx.x >> 6, lane = threadIdx.x & 63;
    int fr = lane & 15, kg = lane >> 4;
    int wm = m0 + wave * 16;
    const ushort* WT = (which == 0 ? WqT : which == 1 ? WkT : WvT) + (long)h * 64 * 128;
    const float* bias = (which == 0 ? bq : which == 1 ? bk : bv) + h * 64;
    f32x4 acc[4] = {};
    for (int k0 = 0; k0 < 128; k0 += 32) {
        bf16x8 a = *(const bf16x8*)(xb + (long)(wm + fr) * 128 + k0 + kg * 8);
#pragma unroll
        for (int t = 0; t < 4; ++t) {
            bf16x8 b = *(const bf16x8*)(WT + (long)(t * 16 + fr) * 128 + k0 + kg * 8);
            acc[t] = __builtin_amdgcn_mfma_f32_16x16x32_bf16(a, b, acc[t], 0, 0, 0);
        }
    }
    int rb = wm + kg * 4;
#pragma unroll
    for (int t = 0; t < 4; ++t) {
        int col = t * 16 + fr;
        float bs = bias[col];
        if (which == 2) {
            ushort4 o;
            o.x = f2bf(fmaxf(acc[t][0] + bs, 0.f));
            o.y = f2bf(fmaxf(acc[t][1] + bs, 0.f));
            o.z = f2bf(fmaxf(acc[t][2] + bs, 0.f));
            o.w = f2bf(fmaxf(acc[t][3] + bs, 0.f));
            *(ushort4*)(vT + ((long)h * 64 + col) * N_TOK + rb) = o;
        } else {
            ushort* dst = (which == 0 ? qb : kb) + (long)h * N_TOK * 64;
            float scl = (which == 0) ? 0.125f : 1.0f;
#pragma unroll
            for (int r = 0; r < 4; ++r)
                dst[(long)(rb + r) * 64 + col] = f2bf(fmaxf(acc[t][r] + bs, 0.f) * scl);
        }
    }
}

// ---------------- flash attention v2: 64q x 64kv tiles, KV-chunked ----------
// LDS swizzle convention: LDS[r][c] = G[r][c ^ ((r&7)*8)]  (c in elements, tile
// row = 64 bf16 = 128B). Staged via global_load_lds with pre-swizzled source.
__global__ __launch_bounds__(256) void attn_flash2(
    const ushort* __restrict__ qb, const ushort* __restrict__ kb,
    const ushort* __restrict__ vT, float* __restrict__ opart,
    float* __restrict__ mlpart) {
    int qt = blockIdx.x, h = blockIdx.y, cz = blockIdx.z;
    int w = threadIdx.x >> 6, lane = threadIdx.x & 63;
    int fr = lane & 15, kg = lane >> 4;
    int lr = lane >> 3, lc = lane & 7;
    int swz = (lc ^ (lr & 7)) * 8;
    __shared__ ushort Kt[2][64 * 64];
    __shared__ ushort Vt[2][64 * 64];
    __shared__ ushort Pl[4][16 * 64];
    const ushort* qh = qb + (long)h * N_TOK * 64;
    const ushort* kh = kb + (long)h * N_TOK * 64;
    const ushort* vh = vT + (long)h * 64 * N_TOK;
    int q0 = qt * 64 + w * 16;
    bf16x8 qf0 = *(const bf16x8*)(qh + (long)(q0 + fr) * 64 + kg * 8);
    bf16x8 qf1 = *(const bf16x8*)(qh + (long)(q0 + fr) * 64 + 32 + kg * 8);
    f32x4 o[4] = {};
    float mrun[4], lrun[4];
#pragma unroll
    for (int r = 0; r < 4; ++r) { mrun[r] = -1e30f; lrun[r] = 0.f; }
    int nbase = cz * (N_TOK / NC_ATT);
    auto stage = [&](int buf, int s) {
        int n0 = nbase + s * 64;
#pragma unroll
        for (int j = 0; j < 2; ++j) {
            int i = w * 2 + j;
            int row = i * 8 + lr;
            __builtin_amdgcn_global_load_lds(
                (const __attribute__((address_space(1))) unsigned int*)(kh + (long)(n0 + row) * 64 + swz),
                (__attribute__((address_space(3))) unsigned int*)(&Kt[buf][i * 512]), 16, 0, 0);
        }
#pragma unroll
        for (int j = 0; j < 2; ++j) {
            int i = w * 2 + j;
            int row = i * 8 + lr;
            __builtin_amdgcn_global_load_lds(
                (const __attribute__((address_space(1))) unsigned int*)(vh + (long)row * N_TOK + n0 + swz),
                (__attribute__((address_space(3))) unsigned int*)(&Vt[buf][i * 512]), 16, 0, 0);
        }
    };
    stage(0, 0);
    __syncthreads();
    const int NS = (N_TOK / NC_ATT) / 64;
    for (int s = 0; s < NS; ++s) {
        int buf = s & 1;
        if (s + 1 < NS) stage(buf ^ 1, s + 1);
        f32x4 sc[4] = {};
#pragma unroll
        for (int t = 0; t < 4; ++t) {
            int row = t * 16 + fr;
            bf16x8 b0 = *(const bf16x8*)(&Kt[buf][row * 64 + ((kg * 8) ^ ((row & 7) * 8))]);
            bf16x8 b1 = *(const bf16x8*)(&Kt[buf][row * 64 + ((32 + kg * 8) ^ ((row & 7) * 8))]);
            sc[t] = __builtin_amdgcn_mfma_f32_16x16x32_bf16(qf0, b0, sc[t], 0, 0, 0);
            sc[t] = __builtin_amdgcn_mfma_f32_16x16x32_bf16(qf1, b1, sc[t], 0, 0, 0);
        }
        float p[4][4], alpha[4];
#pragma unroll
        for (int r = 0; r < 4; ++r) {
            float mx = fmaxf(fmaxf(sc[0][r], sc[1][r]), fmaxf(sc[2][r], sc[3][r]));
#pragma unroll
            for (int off = 1; off < 16; off <<= 1) mx = fmaxf(mx, __shfl_xor(mx, off));
            float mnew = fmaxf(mrun[r], mx);
            alpha[r] = __expf(mrun[r] - mnew);
            float rs = 0.f;
#pragma unroll
            for (int t = 0; t < 4; ++t) { p[t][r] = __expf(sc[t][r] - mnew); rs += p[t][r]; }
#pragma unroll
            for (int off = 1; off < 16; off <<= 1) rs += __shfl_xor(rs, off);
            lrun[r] = lrun[r] * alpha[r] + rs;
            mrun[r] = mnew;
        }
#pragma unroll
        for (int t = 0; t < 4; ++t)
#pragma unroll
            for (int r = 0; r < 4; ++r) o[t][r] *= alpha[r];
#pragma unroll
        for (int t = 0; t < 4; ++t)
#pragma unroll
            for (int r = 0; r < 4; ++r) {
                int row = kg * 4 + r;
                int col = t * 16 + fr;
                Pl[w][row * 64 + (col ^ ((row & 7) * 8))] = f2bf(p[t][r]);
            }
#pragma unroll
        for (int ks = 0; ks < 2; ++ks) {
            bf16x8 pf = *(const bf16x8*)(&Pl[w][fr * 64 + ((ks * 32 + kg * 8) ^ ((fr & 7) * 8))]);
#pragma unroll
            for (int t = 0; t < 4; ++t) {
                int row = t * 16 + fr;
                bf16x8 b = *(const bf16x8*)(&Vt[buf][row * 64 + ((ks * 32 + kg * 8) ^ ((row & 7) * 8))]);
                o[t] = __builtin_amdgcn_mfma_f32_16x16x32_bf16(pf, b, o[t], 0, 0, 0);
            }
        }
        __syncthreads();
    }
    float* ob = opart + (((long)cz * 4 + h) * N_TOK + q0 + kg * 4) * 64;
#pragma unroll
    for (int t = 0; t < 4; ++t)
#pragma unroll
        for (int r = 0; r < 4; ++r)
            ob[(long)r * 64 + t * 16 + fr] = o[t][r];
    if (fr == 0) {
        float* mlb = mlpart + (((long)cz * 4 + h) * N_TOK + q0 + kg * 4) * 2;
#pragma unroll
        for (int r = 0; r < 4; ++r) { mlb[r * 2] = mrun[r]; mlb[r * 2 + 1] = lrun[r]; }
    }
}

// ---------------- combine KV-chunk partials -> mhoT bf16 [256][4096] --------
__global__ __launch_bounds__(256) void attn_combine(
    const float* __restrict__ opart, const float* __restrict__ mlpart,
    ushort* __restrict__ mhoT) {
    int h = blockIdx.y;
    int q0 = blockIdx.x * 64;
    int tid = threadIdx.x;
    int ql = tid >> 4, qv = tid & 15;
    __shared__ ushort tr[64 * 64];
#pragma unroll
    for (int pass = 0; pass < 4; ++pass) {
        int qloc = pass * 16 + ql;
        int q = q0 + qloc;
        float m[NC_ATT], l[NC_ATT], M = -1e30f;
#pragma unroll
        for (int c = 0; c < NC_ATT; ++c) {
            const float* mlb = mlpart + (((long)c * 4 + h) * N_TOK + q) * 2;
            m[c] = mlb[0]; l[c] = mlb[1];
            M = fmaxf(M, m[c]);
        }
        float L = 0.f, wgt[NC_ATT];
#pragma unroll
        for (int c = 0; c < NC_ATT; ++c) { wgt[c] = __expf(m[c] - M); L += l[c] * wgt[c]; }
        float inv = 1.0f / L;
        float ax = 0.f, ay = 0.f, az = 0.f, aw = 0.f;
#pragma unroll
        for (int c = 0; c < NC_ATT; ++c) {
            float4 v = *(const float4*)(opart + (((long)c * 4 + h) * N_TOK + q) * 64 + qv * 4);
            ax += v.x * wgt[c]; ay += v.y * wgt[c]; az += v.z * wgt[c]; aw += v.w * wgt[c];
        }
        tr[(qv * 4 + 0) * 64 + qloc] = f2bf(ax * inv);
        tr[(qv * 4 + 1) * 64 + qloc] = f2bf(ay * inv);
        tr[(qv * 4 + 2) * 64 + qloc] = f2bf(az * inv);
        tr[(qv * 4 + 3) * 64 + qloc] = f2bf(aw * inv);
    }
    __syncthreads();
    int row = tid >> 2, seg = tid & 3;
    *(bf16x8*)(mhoT + (long)(h * 64 + row) * N_TOK + q0 + seg * 16) =
        *(const bf16x8*)(tr + row * 64 + seg * 16);
    *(bf16x8*)(mhoT + (long)(h * 64 + row) * N_TOK + q0 + seg * 16 + 8) =
        *(const bf16x8*)(tr + row * 64 + seg * 16 + 8);
}

// ---------------- big gemm: part[c] = rpeW[.,Kc] @ mhoT[.,Kc]^T -------------
// M-tile 64 (8 waves: 4 m-sub x 2 n-half), N = 256 full, K-chunk 1024.
__global__ __launch_bounds__(512) void gemm_big(
    const ushort* __restrict__ A, const ushort* __restrict__ B,
    float* __restrict__ part) {
    int mt = blockIdx.x, cz = blockIdx.y;
    int w = threadIdx.x >> 6, lane = threadIdx.x & 63;
    int fr = lane & 15, kg = lane >> 4;
    int lr = lane >> 3, lc = lane & 7;
    int swz = (lc ^ (lr & 7)) * 8;
    int ms = w >> 1, nh = w & 1;
    __shared__ ushort Bt[2][256 * 64];
    int m0 = mt * 64;
    long kbase = (long)cz * (4096 / NC_GEMM);
    auto stage = [&](int buf, int s) {
        const ushort* src = B + kbase + s * 64 + swz;
#pragma unroll
        for (int j = 0; j < 4; ++j) {
            int i = w * 4 + j;
            int row = i * 8 + lr;
            __builtin_amdgcn_global_load_lds(
                (const __attribute__((address_space(1))) unsigned int*)(src + (long)row * 4096),
                (__attribute__((address_space(3))) unsigned int*)(&Bt[buf][i * 512]), 16, 0, 0);
        }
    };
    f32x4 acc[8] = {};
    const ushort* Arow = A + (long)(m0 + ms * 16 + fr) * 4096 + kbase + kg * 8;
    stage(0, 0);
    bf16x8 a0 = *(const bf16x8*)(Arow);
    bf16x8 a1 = *(const bf16x8*)(Arow + 32);
    __syncthreads();
    const int NS = (4096 / NC_GEMM) / 64;
    for (int s = 0; s < NS; ++s) {
        int buf = s & 1;
        bf16x8 na0 = a0, na1 = a1;
        if (s + 1 < NS) {
            na0 = *(const bf16x8*)(Arow + (s + 1) * 64);
            na1 = *(const bf16x8*)(Arow + (s + 1) * 64 + 32);
            stage(buf ^ 1, s + 1);
        }
#pragma unroll
        for (int ks = 0; ks < 2; ++ks) {
            bf16x8 av = ks ? a1 : a0;
#pragma unroll
            for (int nf = 0; nf < 8; ++nf) {
                int row = nh * 128 + nf * 16 + fr;
                bf16x8 b = *(const bf16x8*)(&Bt[buf][row * 64 + ((ks * 32 + kg * 8) ^ ((row & 7) * 8))]);
                acc[nf] = __builtin_amdgcn_mfma_f32_16x16x32_bf16(av, b, acc[nf], 0, 0, 0);
            }
        }
        __syncthreads();
        a0 = na0; a1 = na1;
    }
    float* pb = part + ((long)cz * N_TOK + m0 + ms * 16 + kg * 4) * 256 + nh * 128 + fr;
#pragma unroll
    for (int nf = 0; nf < 8; ++nf)
#pragma unroll
        for (int r = 0; r < 4; ++r)
            pb[(long)r * 256 + nf * 16] = acc[nf][r];
}

// ---------------- sum 4 K-chunk partials -> adj bf16 ----------------
__global__ void gemm_combine4(const float* __restrict__ part, ushort* __restrict__ adj) {
    const long TOT = (long)N_TOK * 256 / 4;
    long i = blockIdx.x * (long)blockDim.x + threadIdx.x;
    if (i >= TOT) return;
    const float4* p = (const float4*)part;
    float4 a = p[i];
    float4 b = p[i + TOT];
    float4 c = p[i + 2 * TOT];
    float4 d = p[i + 3 * TOT];
    ushort4 o;
    o.x = f2bf(a.x + b.x + c.x + d.x);
    o.y = f2bf(a.y + b.y + c.y + d.y);
    o.z = f2bf(a.z + b.z + c.z + d.z);
    o.w = f2bf(a.w + b.w + c.w + d.w);
    ((ushort4*)adj)[i] = o;
}

// ---------------- generic gemm_bt: C = act(A @ BT^T + bias [+ res]) ---------
template <int RELU, int OUT_MODE>
__global__ __launch_bounds__(256) void gemm_bt(
    const ushort* __restrict__ A, const ushort* __restrict__ BT,
    const float* __restrict__ bias, void* __restrict__ outp,
    const float* __restrict__ res, int Ncols, int Kd) {
    int m0 = blockIdx.x * 64, n0 = blockIdx.y * 64;
    int wave = threadIdx.x >> 6, lane = threadIdx.x & 63;
    int fr = lane & 15, kg = lane >> 4;
    int wm = m0 + wave * 16;
    f32x4 acc[4] = {};
    for (int k0 = 0; k0 < Kd; k0 += 32) {
        bf16x8 a = *(const bf16x8*)(A + (long)(wm + fr) * Kd + k0 + kg * 8);
#pragma unroll
        for (int t = 0; t < 4; ++t) {
            bf16x8 b = *(const bf16x8*)(BT + (long)(n0 + t * 16 + fr) * Kd + k0 + kg * 8);
            acc[t] = __builtin_amdgcn_mfma_f32_16x16x32_bf16(a, b, acc[t], 0, 0, 0);
        }
    }
    int rb = wm + kg * 4;
#pragma unroll
    for (int t = 0; t < 4; ++t) {
        int col = n0 + t * 16 + fr;
        float bs = bias ? bias[col] : 0.f;
#pragma unroll
        for (int r = 0; r < 4; ++r) {
            float v = acc[t][r] + bs;
            if (RELU) v = fmaxf(v, 0.f);
            long off = (long)(rb + r) * Ncols + col;
            if (OUT_MODE == 0) ((ushort*)outp)[off] = f2bf(v);
            else ((float*)outp)[off] = v + res[off];
        }
    }
}

// ---------------- layernorm over D=128, 1 wave per row ----------------
template <int WF, int WB>
__global__ __launch_bounds__(64) void layer_norm_k(
    const float* __restrict__ src, const float* __restrict__ g, const float* __restrict__ b,
    float* __restrict__ dstf, ushort* __restrict__ dstb) {
    int row = blockIdx.x, lane = threadIdx.x;
    float2 v = *(const float2*)(src + (long)row * 128 + lane * 2);
    float s = v.x + v.y;
#pragma unroll
    for (int off = 32; off >= 1; off >>= 1) s += __shfl_xor(s, off);
    float mean = s * (1.0f / 128.0f);
    float d0 = v.x - mean, d1 = v.y - mean;
    float ss = d0 * d0 + d1 * d1;
#pragma unroll
    for (int off = 32; off >= 1; off >>= 1) ss += __shfl_xor(ss, off);
    float rstd = rsqrtf(ss * (1.0f / 128.0f) + 1e-5f);
    float y0 = d0 * rstd * g[lane * 2] + b[lane * 2];
    float y1 = d1 * rstd * g[lane * 2 + 1] + b[lane * 2 + 1];
    if (WF) {
        float2 o; o.x = y0; o.y = y1;
        *(float2*)(dstf + (long)row * 128 + lane * 2) = o;
    }
    if (WB) {
        ushort2 o; o.x = f2bf(y0); o.y = f2bf(y1);
        *(ushort2*)(dstb + (long)row * 128 + lane * 2) = o;
    }
}

extern "C" void kernel_launch(void* const* d_in, const int* in_sizes, int n_in,
                              void* d_out, int out_size, void* d_ws, size_t ws_size,
                              hipStream_t stream) {
    const float* x     = (const float*)d_in[0];
    const float* rpe   = (const float*)d_in[1];
    const float* Wq    = (const float*)d_in[2];
    const float* bq    = (const float*)d_in[3];
    const float* Wk    = (const float*)d_in[4];
    const float* bk    = (const float*)d_in[5];
    const float* Wv    = (const float*)d_in[6];
    const float* bv    = (const float*)d_in[7];
    const float* rpe_w = (const float*)d_in[8];
    const float* rpe_b = (const float*)d_in[9];
    const float* Wo    = (const float*)d_in[10];
    const float* bo    = (const float*)d_in[11];
    const float* W1    = (const float*)d_in[12];
    const float* b1    = (const float*)d_in[13];
    const float* W2    = (const float*)d_in[14];
    const float* b2    = (const float*)d_in[15];
    const float* g1    = (const float*)d_in[16];
    const float* lb1   = (const float*)d_in[17];
    const float* g2    = (const float*)d_in[18];
    const float* lb2   = (const float*)d_in[19];

    char* wp = (char*)d_ws;
    auto alloc = [&](size_t sz) { char* p = wp; wp += (sz + 255) & ~(size_t)255; return p; };
    ushort* xb    = (ushort*)alloc((size_t)4096 * 128 * 2);
    ushort* WqT   = (ushort*)alloc((size_t)4 * 64 * 128 * 2);
    ushort* WkT   = (ushort*)alloc((size_t)4 * 64 * 128 * 2);
    ushort* WvT   = (ushort*)alloc((size_t)4 * 64 * 128 * 2);
    ushort* WoT   = (ushort*)alloc((size_t)128 * 256 * 2);
    ushort* W1T   = (ushort*)alloc((size_t)256 * 128 * 2);
    ushort* W2T   = (ushort*)alloc((size_t)128 * 256 * 2);
    ushort* qb    = (ushort*)alloc((size_t)4 * 4096 * 64 * 2);
    ushort* kbuf  = (ushort*)alloc((size_t)4 * 4096 * 64 * 2);
    ushort* vT    = (ushort*)alloc((size_t)4 * 64 * 4096 * 2);
    ushort* rpeW  = (ushort*)alloc((size_t)4096 * 4096 * 2);
    ushort* mhoT  = (ushort*)alloc((size_t)256 * 4096 * 2);
    ushort* adj   = (ushort*)alloc((size_t)4096 * 256 * 2);
    float*  res1  = (float*)alloc((size_t)4096 * 128 * 4);
    float*  x1f   = (float*)alloc((size_t)4096 * 128 * 4);
    ushort* x1b   = (ushort*)alloc((size_t)4096 * 128 * 2);
    ushort* h1    = (ushort*)alloc((size_t)4096 * 256 * 2);
    float*  res2  = (float*)alloc((size_t)4096 * 128 * 4);
    float*  opart = (float*)alloc((size_t)NC_ATT * 4 * 4096 * 64 * 4);
    float*  mlprt = (float*)alloc((size_t)NC_ATT * 4 * 4096 * 2 * 4);
    float*  gpart = (float*)alloc((size_t)NC_GEMM * 4096 * 256 * 4);

    cast_f32_bf16<<<512, 256, 0, stream>>>(x, xb, 4096 * 128 / 4);
    transpose_f32_bf16<<<dim3(32, 4), 256, 0, stream>>>(Wq, WqT, 128, 64);
    transpose_f32_bf16<<<dim3(32, 4), 256, 0, stream>>>(Wk, WkT, 128, 64);
    transpose_f32_bf16<<<dim3(32, 4), 256, 0, stream>>>(Wv, WvT, 128, 64);
    transpose_f32_bf16<<<dim3(128, 1), 256, 0, stream>>>(Wo, WoT, 256, 128);
    transpose_f32_bf16<<<dim3(128, 1), 256, 0, stream>>>(W1, W1T, 128, 256);
    transpose_f32_bf16<<<dim3(128, 1), 256, 0, stream>>>(W2, W2T, 256, 128);
    rpe_reduce<<<2048, 256, 0, stream>>>(rpe, rpe_w, rpe_b, rpeW);
    qkv_proj<<<dim3(64, 12), 256, 0, stream>>>(xb, WqT, WkT, WvT, bq, bk, bv, qb, kbuf, vT);
    attn_flash2<<<dim3(64, 4, NC_ATT), 256, 0, stream>>>(qb, kbuf, vT, opart, mlprt);
    attn_combine<<<dim3(64, 4), 256, 0, stream>>>(opart, mlprt, mhoT);
    gemm_big<<<dim3(64, NC_GEMM), 512, 0, stream>>>(rpeW, mhoT, gpart);
    gemm_combine4<<<1024, 256, 0, stream>>>(gpart, adj);
    gemm_bt<0, 1><<<dim3(64, 2), 256, 0, stream>>>(adj, WoT, bo, res1, x, 128, 256);
    layer_norm_k<1, 1><<<4096, 64, 0, stream>>>(res1, g1, lb1, x1f, x1b);
    gemm_bt<1, 0><<<dim3(64, 4), 256, 0, stream>>>(x1b, W1T, b1, h1, nullptr, 256, 128);
    gemm_bt<0, 1><<<dim3(64, 2), 256, 0, stream>>>(h1, W2T, b2, res2, x1f, 128, 256);
    layer_norm_k<1, 0><<<4096, 64, 0, stream>>>(res2, g2, lb2, (float*)d_out, nullptr);
}

// Round 4
// 169.204 us; speedup vs baseline: 2.2965x; 1.4030x over previous
//
#include <hip/hip_runtime.h>

typedef __attribute__((ext_vector_type(8))) short bf16x8;
typedef __attribute__((ext_vector_type(4))) float f32x4;

#define N_TOK 4096
#define NC_ATT 4
#define NC_GEMM 8

static __device__ __forceinline__ ushort f2bf(float f) {
    union { float f; unsigned u; } x; x.f = f;
    unsigned u = x.u;
    unsigned r = (u + 0x7FFFu + ((u >> 16) & 1u)) >> 16;
    return (ushort)r;
}
static __device__ __forceinline__ unsigned pkbf(float a, float b) {
    return (unsigned)f2bf(a) | ((unsigned)f2bf(b) << 16);
}

// ---------------- prep: cast x + all 6 weight transposes in one kernel ------
__global__ void prep_all(const float* __restrict__ x,
                         const float* __restrict__ Wq, const float* __restrict__ Wk,
                         const float* __restrict__ Wv, const float* __restrict__ Wo,
                         const float* __restrict__ W1, const float* __restrict__ W2,
                         ushort* __restrict__ xb, ushort* __restrict__ WqT,
                         ushort* __restrict__ WkT, ushort* __restrict__ WvT,
                         ushort* __restrict__ WoT, ushort* __restrict__ W1T,
                         ushort* __restrict__ W2T) {
    int i = blockIdx.x * 256 + threadIdx.x;
    if (i < 131072) {  // x: 4096*128/4 quads
        float4 v = ((const float4*)x)[i];
        ushort4 o;
        o.x = f2bf(v.x); o.y = f2bf(v.y); o.z = f2bf(v.z); o.w = f2bf(v.w);
        ((ushort4*)xb)[i] = o;
        return;
    }
    int j = i - 131072;
    int t = j >> 15, e = j & 32767;
    if (t < 3) {  // Wq/Wk/Wv [4][128][64] -> [4][64][128]
        const float* src = (t == 0 ? Wq : t == 1 ? Wk : Wv);
        ushort* dst = (t == 0 ? WqT : t == 1 ? WkT : WvT);
        int h = e >> 13, rem = e & 8191, d = rem >> 6, k = rem & 63;
        dst[h * 8192 + k * 128 + d] = f2bf(src[e]);
    } else if (t == 3) {  // Wo [256][128] -> [128][256]
        int r = e >> 7, c = e & 127;
        WoT[c * 256 + r] = f2bf(Wo[e]);
    } else if (t == 4) {  // W1 [128][256] -> [256][128]
        int r = e >> 8, c = e & 255;
        W1T[c * 128 + r] = f2bf(W1[e]);
    } else {  // W2 [256][128] -> [128][256]
        int r = e >> 7, c = e & 127;
        W2T[c * 256 + r] = f2bf(W2[e]);
    }
}

// ---------------- QKV projection: relu(xb @ W^T + b), q pre-scaled 0.125 ----
__global__ __launch_bounds__(256) void qkv_proj(
    const ushort* __restrict__ xb, const ushort* __restrict__ WqT,
    const ushort* __restrict__ WkT, const ushort* __restrict__ WvT,
    const float* __restrict__ bq, const float* __restrict__ bk, const float* __restrict__ bv,
    ushort* __restrict__ qb, ushort* __restrict__ kb, ushort* __restrict__ vT) {
    int m0 = blockIdx.x * 64;
    int h = blockIdx.y & 3, which = blockIdx.y >> 2;
    int wave = threadIdx.x >> 6, lane = threadIdx.x & 63;
    int fr = lane & 15, kg = lane >> 4;
    int wm = m0 + wave * 16;
    const ushort* WT = (which == 0 ? WqT : which == 1 ? WkT : WvT) + (long)h * 64 * 128;
    const float* bias = (which == 0 ? bq : which == 1 ? bk : bv) + h * 64;
    f32x4 acc[4] = {};
    for (int k0 = 0; k0 < 128; k0 += 32) {
        bf16x8 a = *(const bf16x8*)(xb + (long)(wm + fr) * 128 + k0 + kg * 8);
#pragma unroll
        for (int t = 0; t < 4; ++t) {
            bf16x8 b = *(const bf16x8*)(WT + (long)(t * 16 + fr) * 128 + k0 + kg * 8);
            acc[t] = __builtin_amdgcn_mfma_f32_16x16x32_bf16(a, b, acc[t], 0, 0, 0);
        }
    }
    int rb = wm + kg * 4;
#pragma unroll
    for (int t = 0; t < 4; ++t) {
        int col = t * 16 + fr;
        float bs = bias[col];
        if (which == 2) {
            ushort4 o;
            o.x = f2bf(fmaxf(acc[t][0] + bs, 0.f));
            o.y = f2bf(fmaxf(acc[t][1] + bs, 0.f));
            o.z = f2bf(fmaxf(acc[t][2] + bs, 0.f));
            o.w = f2bf(fmaxf(acc[t][3] + bs, 0.f));
            *(ushort4*)(vT + ((long)h * 64 + col) * N_TOK + rb) = o;
        } else {
            ushort* dst = (which == 0 ? qb : kb) + (long)h * N_TOK * 64;
            float scl = (which == 0) ? 0.125f : 1.0f;
#pragma unroll
            for (int r = 0; r < 4; ++r)
                dst[(long)(rb + r) * 64 + col] = f2bf(fmaxf(acc[t][r] + bs, 0.f) * scl);
        }
    }
}

// ---------------- flash attention v3: swapped QK^T (lane-local softmax) -----
__global__ __launch_bounds__(256) void attn_flash2(
    const ushort* __restrict__ qb, const ushort* __restrict__ kb,
    const ushort* __restrict__ vT, float* __restrict__ opart,
    float* __restrict__ mlpart) {
    int qt = blockIdx.x, h = blockIdx.y, cz = blockIdx.z;
    int w = threadIdx.x >> 6, lane = threadIdx.x & 63;
    int fr = lane & 15, kg = lane >> 4;
    int lr = lane >> 3, lc = lane & 7;
    int swz = (lc ^ (lr & 7)) * 8;
    __shared__ ushort Kt[2][64 * 64];
    __shared__ ushort Vt[2][64 * 64];
    __shared__ ushort Pl[4][16 * 64];
    const ushort* qh = qb + (long)h * N_TOK * 64;
    const ushort* kh = kb + (long)h * N_TOK * 64;
    const ushort* vh = vT + (long)h * 64 * N_TOK;
    int q0 = qt * 64 + w * 16;
    bf16x8 qf0 = *(const bf16x8*)(qh + (long)(q0 + fr) * 64 + kg * 8);
    bf16x8 qf1 = *(const bf16x8*)(qh + (long)(q0 + fr) * 64 + 32 + kg * 8);
    f32x4 o[4] = {};
    float mrun = -1e30f, lrun = 0.f;  // per-lane stats for q = q0 + fr
    int nbase = cz * (N_TOK / NC_ATT);
    auto stage = [&](int buf, int s) {
        int n0 = nbase + s * 64;
#pragma unroll
        for (int j = 0; j < 2; ++j) {
            int i = w * 2 + j;
            int row = i * 8 + lr;
            __builtin_amdgcn_global_load_lds(
                (const __attribute__((address_space(1))) unsigned int*)(kh + (long)(n0 + row) * 64 + swz),
                (__attribute__((address_space(3))) unsigned int*)(&Kt[buf][i * 512]), 16, 0, 0);
        }
#pragma unroll
        for (int j = 0; j < 2; ++j) {
            int i = w * 2 + j;
            int row = i * 8 + lr;
            __builtin_amdgcn_global_load_lds(
                (const __attribute__((address_space(1))) unsigned int*)(vh + (long)row * N_TOK + n0 + swz),
                (__attribute__((address_space(3))) unsigned int*)(&Vt[buf][i * 512]), 16, 0, 0);
        }
    };
    stage(0, 0);
    __syncthreads();
    const int NS = (N_TOK / NC_ATT) / 64;
    for (int s = 0; s < NS; ++s) {
        int buf = s & 1;
        if (s + 1 < NS) stage(buf ^ 1, s + 1);
        // S^T = K @ Q^T: lane holds kv = t*16+kg*4+r for q = q0+fr
        f32x4 sc[4] = {};
#pragma unroll
        for (int t = 0; t < 4; ++t) {
            int row = t * 16 + fr;
            bf16x8 k0 = *(const bf16x8*)(&Kt[buf][row * 64 + ((kg * 8) ^ ((row & 7) * 8))]);
            bf16x8 k1 = *(const bf16x8*)(&Kt[buf][row * 64 + ((32 + kg * 8) ^ ((row & 7) * 8))]);
            sc[t] = __builtin_amdgcn_mfma_f32_16x16x32_bf16(k0, qf0, sc[t], 0, 0, 0);
            sc[t] = __builtin_amdgcn_mfma_f32_16x16x32_bf16(k1, qf1, sc[t], 0, 0, 0);
        }
        float mx = sc[0][0];
#pragma unroll
        for (int t = 0; t < 4; ++t)
#pragma unroll
            for (int r = 0; r < 4; ++r) mx = fmaxf(mx, sc[t][r]);
        mx = fmaxf(mx, __shfl_xor(mx, 16));
        mx = fmaxf(mx, __shfl_xor(mx, 32));
        float mnew = fmaxf(mrun, mx);
        float alpha = __expf(mrun - mnew);
        float rs = 0.f;
#pragma unroll
        for (int t = 0; t < 4; ++t)
#pragma unroll
            for (int r = 0; r < 4; ++r) {
                float p = __expf(sc[t][r] - mnew);
                sc[t][r] = p;
                rs += p;
            }
        rs += __shfl_xor(rs, 16);
        rs += __shfl_xor(rs, 32);
        lrun = lrun * alpha + rs;
        mrun = mnew;
        float aq[4];
#pragma unroll
        for (int r = 0; r < 4; ++r) aq[r] = __shfl(alpha, kg * 4 + r);
#pragma unroll
        for (int t = 0; t < 4; ++t)
#pragma unroll
            for (int r = 0; r < 4; ++r) o[t][r] *= aq[r];
        // P[q=fr][kv]: pack 4 consecutive kv per tile -> b64 write
#pragma unroll
        for (int t = 0; t < 4; ++t) {
            uint2 u;
            u.x = pkbf(sc[t][0], sc[t][1]);
            u.y = pkbf(sc[t][2], sc[t][3]);
            *(uint2*)(&Pl[w][fr * 64 + ((t * 16 + kg * 4) ^ ((fr & 7) * 8))]) = u;
        }
#pragma unroll
        for (int ks = 0; ks < 2; ++ks) {
            bf16x8 pf = *(const bf16x8*)(&Pl[w][fr * 64 + ((ks * 32 + kg * 8) ^ ((fr & 7) * 8))]);
#pragma unroll
            for (int t = 0; t < 4; ++t) {
                int row = t * 16 + fr;
                bf16x8 b = *(const bf16x8*)(&Vt[buf][row * 64 + ((ks * 32 + kg * 8) ^ ((row & 7) * 8))]);
                o[t] = __builtin_amdgcn_mfma_f32_16x16x32_bf16(pf, b, o[t], 0, 0, 0);
            }
        }
        __syncthreads();
    }
    float linv = 1.0f / lrun;
    float lq[4];
#pragma unroll
    for (int r = 0; r < 4; ++r) lq[r] = __shfl(linv, kg * 4 + r);
    float* ob = opart + (((long)cz * 4 + h) * N_TOK + q0 + kg * 4) * 64;
#pragma unroll
    for (int t = 0; t < 4; ++t)
#pragma unroll
        for (int r = 0; r < 4; ++r)
            ob[(long)r * 64 + t * 16 + fr] = o[t][r] * lq[r];
    if (lane < 16) {
        float* mlb = mlpart + (((long)cz * 4 + h) * N_TOK + q0 + lane) * 2;
        mlb[0] = mrun;
        mlb[1] = lrun * linv == 1.f ? lrun : lrun;  // keep lrun
    }
}

// ---------------- combine KV-chunk partials -> mhoT bf16 [256][4096] --------
__global__ __launch_bounds__(256) void attn_combine(
    const float* __restrict__ opart, const float* __restrict__ mlpart,
    ushort* __restrict__ mhoT) {
    int h = blockIdx.y;
    int q0 = blockIdx.x * 64;
    int tid = threadIdx.x;
    int ql = tid >> 4, qv = tid & 15;
    __shared__ ushort tr[64 * 64];
#pragma unroll
    for (int pass = 0; pass < 4; ++pass) {
        int qloc = pass * 16 + ql;
        int q = q0 + qloc;
        float m[NC_ATT], l[NC_ATT], M = -1e30f;
#pragma unroll
        for (int c = 0; c < NC_ATT; ++c) {
            const float* mlb = mlpart + (((long)c * 4 + h) * N_TOK + q) * 2;
            m[c] = mlb[0]; l[c] = mlb[1];
            M = fmaxf(M, m[c]);
        }
        float L = 0.f, wgt[NC_ATT];
#pragma unroll
        for (int c = 0; c < NC_ATT; ++c) { wgt[c] = __expf(m[c] - M); L += l[c] * wgt[c]; }
        float inv = 1.0f / L;
#pragma unroll
        for (int c = 0; c < NC_ATT; ++c) wgt[c] *= l[c] * inv;
        float ax = 0.f, ay = 0.f, az = 0.f, aw = 0.f;
#pragma unroll
        for (int c = 0; c < NC_ATT; ++c) {
            float4 v = *(const float4*)(opart + (((long)c * 4 + h) * N_TOK + q) * 64 + qv * 4);
            ax += v.x * wgt[c]; ay += v.y * wgt[c]; az += v.z * wgt[c]; aw += v.w * wgt[c];
        }
        tr[(qv * 4 + 0) * 64 + qloc] = f2bf(ax);
        tr[(qv * 4 + 1) * 64 + qloc] = f2bf(ay);
        tr[(qv * 4 + 2) * 64 + qloc] = f2bf(az);
        tr[(qv * 4 + 3) * 64 + qloc] = f2bf(aw);
    }
    __syncthreads();
    int row = tid >> 2, seg = tid & 3;
    *(bf16x8*)(mhoT + (long)(h * 64 + row) * N_TOK + q0 + seg * 16) =
        *(const bf16x8*)(tr + row * 64 + seg * 16);
    *(bf16x8*)(mhoT + (long)(h * 64 + row) * N_TOK + q0 + seg * 16 + 8) =
        *(const bf16x8*)(tr + row * 64 + seg * 16 + 8);
}

// ---------------- fused: part[c] = (sum_f w_f*rpe[f] + b)[.,Kc] @ mhoT^T ----
__global__ __launch_bounds__(512) void gemm_big_fused(
    const float* __restrict__ rpe, const float* __restrict__ rpe_w,
    const float* __restrict__ rpe_b, const ushort* __restrict__ B,
    float* __restrict__ part) {
    int mt = blockIdx.x, cz = blockIdx.y;
    int tid = threadIdx.x;
    int w = tid >> 6, lane = tid & 63;
    int fr = lane & 15, kg = lane >> 4;
    int lr = lane >> 3, lc = lane & 7;
    int swz = (lc ^ (lr & 7)) * 8;
    int ms = w >> 1, nh = w & 1;
    __shared__ ushort Bt[2][256 * 64];
    __shared__ ushort At[2][64 * 64];
    int m0 = mt * 64;
    long kbase = (long)cz * (N_TOK / NC_GEMM);
    float w0 = rpe_w[0], w1 = rpe_w[1], w2 = rpe_w[2], w3 = rpe_w[3], w4 = rpe_w[4];
    float bb = rpe_b[0];
    auto stage_B = [&](int buf, int s) {
        const ushort* src = B + kbase + s * 64 + swz;
#pragma unroll
        for (int j = 0; j < 4; ++j) {
            int i = w * 4 + j;
            int row = i * 8 + lr;
            __builtin_amdgcn_global_load_lds(
                (const __attribute__((address_space(1))) unsigned int*)(src + (long)row * N_TOK),
                (__attribute__((address_space(3))) unsigned int*)(&Bt[buf][i * 512]), 16, 0, 0);
        }
    };
    auto stage_A = [&](int buf, int s) {
        const float* base = rpe + (long)m0 * N_TOK + kbase + s * 64;
#pragma unroll
        for (int rnd = 0; rnd < 2; ++rnd) {
            int idx = tid + rnd * 512;
            int row = idx >> 4, c4 = (idx & 15) * 4;
            const float* pr = base + (long)row * N_TOK + c4;
            float4 p0 = *(const float4*)(pr);
            float4 p1 = *(const float4*)(pr + (1L << 24));
            float4 p2 = *(const float4*)(pr + (2L << 24));
            float4 p3 = *(const float4*)(pr + (3L << 24));
            float4 p4 = *(const float4*)(pr + (4L << 24));
            float v0 = bb + w0 * p0.x + w1 * p1.x + w2 * p2.x + w3 * p3.x + w4 * p4.x;
            float v1 = bb + w0 * p0.y + w1 * p1.y + w2 * p2.y + w3 * p3.y + w4 * p4.y;
            float v2 = bb + w0 * p0.z + w1 * p1.z + w2 * p2.z + w3 * p3.z + w4 * p4.z;
            float v3 = bb + w0 * p0.w + w1 * p1.w + w2 * p2.w + w3 * p3.w + w4 * p4.w;
            uint2 u;
            u.x = pkbf(v0, v1);
            u.y = pkbf(v2, v3);
            *(uint2*)(&At[buf][row * 64 + (c4 ^ ((row & 7) * 8))]) = u;
        }
    };
    f32x4 acc[8] = {};
    stage_B(0, 0);
    stage_A(0, 0);
    __syncthreads();
    const int NS = (N_TOK / NC_GEMM) / 64;
    int arow = ms * 16 + fr;
    for (int s = 0; s < NS; ++s) {
        int buf = s & 1;
        if (s + 1 < NS) { stage_B(buf ^ 1, s + 1); stage_A(buf ^ 1, s + 1); }
#pragma unroll
        for (int ks = 0; ks < 2; ++ks) {
            bf16x8 av = *(const bf16x8*)(&At[buf][arow * 64 + ((ks * 32 + kg * 8) ^ ((arow & 7) * 8))]);
#pragma unroll
            for (int nf = 0; nf < 8; ++nf) {
                int row = nh * 128 + nf * 16 + fr;
                bf16x8 b = *(const bf16x8*)(&Bt[buf][row * 64 + ((ks * 32 + kg * 8) ^ ((row & 7) * 8))]);
                acc[nf] = __builtin_amdgcn_mfma_f32_16x16x32_bf16(av, b, acc[nf], 0, 0, 0);
            }
        }
        __syncthreads();
    }
    float* pb = part + ((long)cz * N_TOK + m0 + ms * 16 + kg * 4) * 256 + nh * 128 + fr;
#pragma unroll
    for (int nf = 0; nf < 8; ++nf)
#pragma unroll
        for (int r = 0; r < 4; ++r)
            pb[(long)r * 256 + nf * 16] = acc[nf][r];
}

// ---------------- sum NC_GEMM K-chunk partials -> adj bf16 ----------------
__global__ void gemm_combine(const float* __restrict__ part, ushort* __restrict__ adj) {
    const long TOT = (long)N_TOK * 256 / 4;
    long i = blockIdx.x * (long)blockDim.x + threadIdx.x;
    if (i >= TOT) return;
    const float4* p = (const float4*)part;
    float sx = 0.f, sy = 0.f, sz = 0.f, sw = 0.f;
#pragma unroll
    for (int c = 0; c < NC_GEMM; ++c) {
        float4 v = p[i + c * TOT];
        sx += v.x; sy += v.y; sz += v.z; sw += v.w;
    }
    ushort4 o;
    o.x = f2bf(sx); o.y = f2bf(sy); o.z = f2bf(sz); o.w = f2bf(sw);
    ((ushort4*)adj)[i] = o;
}

// ---------------- megatail: adj@Wo+bo+x -> LN1 -> FFN -> LN2 -> out ---------
__global__ __launch_bounds__(256) void megatail(
    const ushort* __restrict__ adj, const ushort* __restrict__ WoT,
    const float* __restrict__ bo, const float* __restrict__ x,
    const float* __restrict__ g1, const float* __restrict__ lb1,
    const ushort* __restrict__ W1T, const float* __restrict__ b1,
    const ushort* __restrict__ W2T, const float* __restrict__ b2,
    const float* __restrict__ g2, const float* __restrict__ lb2,
    float* __restrict__ out) {
    int r0 = blockIdx.x * 16;
    int tid = threadIdx.x;
    int w = tid >> 6, lane = tid & 63;
    int fr = lane & 15, kg = lane >> 4;
    __shared__ float x1f[16][132];
    __shared__ ushort x1b[16][128];
    __shared__ ushort hbuf[16][256];
    __shared__ float otile[16][132];
    // phase 0: proj = adj @ WoT^T  (wave w -> out cols w*32..w*32+31)
    {
        f32x4 a0[2] = {};
#pragma unroll
        for (int ks = 0; ks < 8; ++ks) {
            bf16x8 a = *(const bf16x8*)(adj + (long)(r0 + fr) * 256 + ks * 32 + kg * 8);
#pragma unroll
            for (int t = 0; t < 2; ++t) {
                bf16x8 b = *(const bf16x8*)(WoT + (long)(w * 32 + t * 16 + fr) * 256 + ks * 32 + kg * 8);
                a0[t] = __builtin_amdgcn_mfma_f32_16x16x32_bf16(a, b, a0[t], 0, 0, 0);
            }
        }
#pragma unroll
        for (int t = 0; t < 2; ++t) {
            int col = w * 32 + t * 16 + fr;
            float bs = bo[col];
#pragma unroll
            for (int r = 0; r < 4; ++r) {
                int row = kg * 4 + r;
                x1f[row][col] = a0[t][r] + bs + x[(long)(r0 + row) * 128 + col];
            }
        }
    }
    __syncthreads();
    // phase 0b: LN1 (16 threads/row, 8 cols each) -> x1f (fp32) + x1b (bf16 swz)
    {
        int row = tid >> 4, c0 = (tid & 15) * 8;
        float v[8];
        float s = 0.f;
#pragma unroll
        for (int jj = 0; jj < 8; ++jj) { v[jj] = x1f[row][c0 + jj]; s += v[jj]; }
#pragma unroll
        for (int off = 1; off < 16; off <<= 1) s += __shfl_xor(s, off);
        float mean = s * (1.0f / 128.0f);
        float ss = 0.f;
#pragma unroll
        for (int jj = 0; jj < 8; ++jj) { float d = v[jj] - mean; ss += d * d; }
#pragma unroll
        for (int off = 1; off < 16; off <<= 1) ss += __shfl_xor(ss, off);
        float rstd = rsqrtf(ss * (1.0f / 128.0f) + 1e-5f);
        union { bf16x8 vec; ushort us[8]; } pk8;
#pragma unroll
        for (int jj = 0; jj < 8; ++jj) {
            float y = (v[jj] - mean) * rstd * g1[c0 + jj] + lb1[c0 + jj];
            x1f[row][c0 + jj] = y;
            pk8.us[jj] = f2bf(y);
        }
        *(bf16x8*)(&x1b[row][c0 ^ ((row & 7) * 8)]) = pk8.vec;
    }
    __syncthreads();
    // phase 1: h = relu(x1b @ W1T^T + b1)  (wave w -> cols w*64..w*64+63)
    {
        f32x4 a1[4] = {};
#pragma unroll
        for (int ks = 0; ks < 4; ++ks) {
            bf16x8 a = *(const bf16x8*)(&x1b[fr][(ks * 32 + kg * 8) ^ ((fr & 7) * 8)]);
#pragma unroll
            for (int t = 0; t < 4; ++t) {
                bf16x8 b = *(const bf16x8*)(W1T + (long)(w * 64 + t * 16 + fr) * 128 + ks * 32 + kg * 8);
                a1[t] = __builtin_amdgcn_mfma_f32_16x16x32_bf16(a, b, a1[t], 0, 0, 0);
            }
        }
#pragma unroll
        for (int t = 0; t < 4; ++t) {
            int col = w * 64 + t * 16 + fr;
            float bs = b1[col];
#pragma unroll
            for (int r = 0; r < 4; ++r) {
                int row = kg * 4 + r;
                hbuf[row][col ^ ((row & 7) * 8)] = f2bf(fmaxf(a1[t][r] + bs, 0.f));
            }
        }
    }
    __syncthreads();
    // phase 2: o = h @ W2T^T + b2 + x1  (wave w -> cols w*32..w*32+31)
    {
        f32x4 a2[2] = {};
#pragma unroll
        for (int ks = 0; ks < 8; ++ks) {
            bf16x8 a = *(const bf16x8*)(&hbuf[fr][(ks * 32 + kg * 8) ^ ((fr & 7) * 8)]);
#pragma unroll
            for (int t = 0; t < 2; ++t) {
                bf16x8 b = *(const bf16x8*)(W2T + (long)(w * 32 + t * 16 + fr) * 256 + ks * 32 + kg * 8);
                a2[t] = __builtin_amdgcn_mfma_f32_16x16x32_bf16(a, b, a2[t], 0, 0, 0);
            }
        }
#pragma unroll
        for (int t = 0; t < 2; ++t) {
            int col = w * 32 + t * 16 + fr;
            float bs = b2[col];
#pragma unroll
            for (int r = 0; r < 4; ++r) {
                int row = kg * 4 + r;
                otile[row][col] = a2[t][r] + bs + x1f[row][col];
            }
        }
    }
    __syncthreads();
    // phase 2b: LN2 -> out fp32
    {
        int row = tid >> 4, c0 = (tid & 15) * 8;
        float v[8];
        float s = 0.f;
#pragma unroll
        for (int jj = 0; jj < 8; ++jj) { v[jj] = otile[row][c0 + jj]; s += v[jj]; }
#pragma unroll
        for (int off = 1; off < 16; off <<= 1) s += __shfl_xor(s, off);
        float mean = s * (1.0f / 128.0f);
        float ss = 0.f;
#pragma unroll
        for (int jj = 0; jj < 8; ++jj) { float d = v[jj] - mean; ss += d * d; }
#pragma unroll
        for (int off = 1; off < 16; off <<= 1) ss += __shfl_xor(ss, off);
        float rstd = rsqrtf(ss * (1.0f / 128.0f) + 1e-5f);
#pragma unroll
        for (int jj = 0; jj < 8; ++jj) {
            float y = (v[jj] - mean) * rstd * g2[c0 + jj] + lb2[c0 + jj];
            out[(long)(r0 + row) * 128 + c0 + jj] = y;
        }
    }
}

extern "C" void kernel_launch(void* const* d_in, const int* in_sizes, int n_in,
                              void* d_out, int out_size, void* d_ws, size_t ws_size,
                              hipStream_t stream) {
    const float* x     = (const float*)d_in[0];
    const float* rpe   = (const float*)d_in[1];
    const float* Wq    = (const float*)d_in[2];
    const float* bq    = (const float*)d_in[3];
    const float* Wk    = (const float*)d_in[4];
    const float* bk    = (const float*)d_in[5];
    const float* Wv    = (const float*)d_in[6];
    const float* bv    = (const float*)d_in[7];
    const float* rpe_w = (const float*)d_in[8];
    const float* rpe_b = (const float*)d_in[9];
    const float* Wo    = (const float*)d_in[10];
    const float* bo    = (const float*)d_in[11];
    const float* W1    = (const float*)d_in[12];
    const float* b1    = (const float*)d_in[13];
    const float* W2    = (const float*)d_in[14];
    const float* b2    = (const float*)d_in[15];
    const float* g1    = (const float*)d_in[16];
    const float* lb1   = (const float*)d_in[17];
    const float* g2    = (const float*)d_in[18];
    const float* lb2   = (const float*)d_in[19];

    char* wp = (char*)d_ws;
    auto alloc = [&](size_t sz) { char* p = wp; wp += (sz + 255) & ~(size_t)255; return p; };
    ushort* xb    = (ushort*)alloc((size_t)4096 * 128 * 2);
    ushort* WqT   = (ushort*)alloc((size_t)4 * 64 * 128 * 2);
    ushort* WkT   = (ushort*)alloc((size_t)4 * 64 * 128 * 2);
    ushort* WvT   = (ushort*)alloc((size_t)4 * 64 * 128 * 2);
    ushort* WoT   = (ushort*)alloc((size_t)128 * 256 * 2);
    ushort* W1T   = (ushort*)alloc((size_t)256 * 128 * 2);
    ushort* W2T   = (ushort*)alloc((size_t)128 * 256 * 2);
    ushort* qb    = (ushort*)alloc((size_t)4 * 4096 * 64 * 2);
    ushort* kbuf  = (ushort*)alloc((size_t)4 * 4096 * 64 * 2);
    ushort* vT    = (ushort*)alloc((size_t)4 * 64 * 4096 * 2);
    ushort* mhoT  = (ushort*)alloc((size_t)256 * 4096 * 2);
    ushort* adj   = (ushort*)alloc((size_t)4096 * 256 * 2);
    float*  opart = (float*)alloc((size_t)NC_ATT * 4 * 4096 * 64 * 4);
    float*  mlprt = (float*)alloc((size_t)NC_ATT * 4 * 4096 * 2 * 4);
    float*  gpart = (float*)alloc((size_t)NC_GEMM * 4096 * 256 * 4);

    prep_all<<<1280, 256, 0, stream>>>(x, Wq, Wk, Wv, Wo, W1, W2,
                                       xb, WqT, WkT, WvT, WoT, W1T, W2T);
    qkv_proj<<<dim3(64, 12), 256, 0, stream>>>(xb, WqT, WkT, WvT, bq, bk, bv, qb, kbuf, vT);
    attn_flash2<<<dim3(64, 4, NC_ATT), 256, 0, stream>>>(qb, kbuf, vT, opart, mlprt);
    attn_combine<<<dim3(64, 4), 256, 0, stream>>>(opart, mlprt, mhoT);
    gemm_big_fused<<<dim3(64, NC_GEMM), 512, 0, stream>>>(rpe, rpe_w, rpe_b, mhoT, gpart);
    gemm_combine<<<1024, 256, 0, stream>>>(gpart, adj);
    megatail<<<256, 256, 0, stream>>>(adj, WoT, bo, x, g1, lb1, W1T, b1, W2T, b2,
                                      g2, lb2, (float*)d_out);
}

// Round 5
// 152.429 us; speedup vs baseline: 2.5492x; 1.1100x over previous
//
#include <hip/hip_runtime.h>

typedef __attribute__((ext_vector_type(8))) short bf16x8;
typedef __attribute__((ext_vector_type(4))) float f32x4;

#define N_TOK 4096
#define NC_ATT 4
#define NC_GEMM 8

static __device__ __forceinline__ ushort f2bf(float f) {
    union { float f; unsigned u; } x; x.f = f;
    unsigned u = x.u;
    unsigned r = (u + 0x7FFFu + ((u >> 16) & 1u)) >> 16;
    return (ushort)r;
}
static __device__ __forceinline__ unsigned pkbf(float a, float b) {
    return (unsigned)f2bf(a) | ((unsigned)f2bf(b) << 16);
}

// ---------------- prep: cast x + all weight transposes in one kernel ------
__global__ void prep_all(const float* __restrict__ x,
                         const float* __restrict__ Wq, const float* __restrict__ Wk,
                         const float* __restrict__ Wv, const float* __restrict__ Wo,
                         const float* __restrict__ W1, const float* __restrict__ W2,
                         ushort* __restrict__ xb, ushort* __restrict__ WqT,
                         ushort* __restrict__ WkT, ushort* __restrict__ WvT,
                         ushort* __restrict__ WoT, ushort* __restrict__ W1T,
                         ushort* __restrict__ W2T) {
    int i = blockIdx.x * 256 + threadIdx.x;
    if (i < 131072) {  // x: 4096*128/4 quads
        float4 v = ((const float4*)x)[i];
        ushort4 o;
        o.x = f2bf(v.x); o.y = f2bf(v.y); o.z = f2bf(v.z); o.w = f2bf(v.w);
        ((ushort4*)xb)[i] = o;
        return;
    }
    int j = i - 131072;
    int t = j >> 15, e = j & 32767;
    if (t < 3) {  // Wq/Wk/Wv [4][128][64] -> [4][64][128]
        const float* src = (t == 0 ? Wq : t == 1 ? Wk : Wv);
        ushort* dst = (t == 0 ? WqT : t == 1 ? WkT : WvT);
        int h = e >> 13, rem = e & 8191, d = rem >> 6, k = rem & 63;
        dst[h * 8192 + k * 128 + d] = f2bf(src[e]);
    } else if (t == 3) {  // Wo [256][128] -> [128][256]
        int r = e >> 7, c = e & 127;
        WoT[c * 256 + r] = f2bf(Wo[e]);
    } else if (t == 4) {  // W1 [128][256] -> [256][128]
        int r = e >> 8, c = e & 255;
        W1T[c * 128 + r] = f2bf(W1[e]);
    } else {  // W2 [256][128] -> [128][256]
        int r = e >> 7, c = e & 127;
        W2T[c * 256 + r] = f2bf(W2[e]);
    }
}

// ---------------- QKV projection: relu(xb @ W^T + b), q pre-scaled 0.125 ----
__global__ __launch_bounds__(256) void qkv_proj(
    const ushort* __restrict__ xb, const ushort* __restrict__ WqT,
    const ushort* __restrict__ WkT, const ushort* __restrict__ WvT,
    const float* __restrict__ bq, const float* __restrict__ bk, const float* __restrict__ bv,
    ushort* __restrict__ qb, ushort* __restrict__ kb, ushort* __restrict__ vT) {
    int m0 = blockIdx.x * 64;
    int h = blockIdx.y & 3, which = blockIdx.y >> 2;
    int wave = threadIdx.x >> 6, lane = threadIdx.x & 63;
    int fr = lane & 15, kg = lane >> 4;
    int wm = m0 + wave * 16;
    const ushort* WT = (which == 0 ? WqT : which == 1 ? WkT : WvT) + (long)h * 64 * 128;
    const float* bias = (which == 0 ? bq : which == 1 ? bk : bv) + h * 64;
    f32x4 acc[4] = {};
    for (int k0 = 0; k0 < 128; k0 += 32) {
        bf16x8 a = *(const bf16x8*)(xb + (long)(wm + fr) * 128 + k0 + kg * 8);
#pragma unroll
        for (int t = 0; t < 4; ++t) {
            bf16x8 b = *(const bf16x8*)(WT + (long)(t * 16 + fr) * 128 + k0 + kg * 8);
            acc[t] = __builtin_amdgcn_mfma_f32_16x16x32_bf16(a, b, acc[t], 0, 0, 0);
        }
    }
    int rb = wm + kg * 4;
#pragma unroll
    for (int t = 0; t < 4; ++t) {
        int col = t * 16 + fr;
        float bs = bias[col];
        if (which == 2) {
            ushort4 o;
            o.x = f2bf(fmaxf(acc[t][0] + bs, 0.f));
            o.y = f2bf(fmaxf(acc[t][1] + bs, 0.f));
            o.z = f2bf(fmaxf(acc[t][2] + bs, 0.f));
            o.w = f2bf(fmaxf(acc[t][3] + bs, 0.f));
            *(ushort4*)(vT + ((long)h * 64 + col) * N_TOK + rb) = o;
        } else {
            ushort* dst = (which == 0 ? qb : kb) + (long)h * N_TOK * 64;
            float scl = (which == 0) ? 0.125f : 1.0f;
#pragma unroll
            for (int r = 0; r < 4; ++r)
                dst[(long)(rb + r) * 64 + col] = f2bf(fmaxf(acc[t][r] + bs, 0.f) * scl);
        }
    }
}

// ---------------- flash attention: swapped QK^T (lane-local softmax) --------
__global__ __launch_bounds__(256) void attn_flash2(
    const ushort* __restrict__ qb, const ushort* __restrict__ kb,
    const ushort* __restrict__ vT, float* __restrict__ opart,
    float* __restrict__ mlpart) {
    int qt = blockIdx.x, h = blockIdx.y, cz = blockIdx.z;
    int w = threadIdx.x >> 6, lane = threadIdx.x & 63;
    int fr = lane & 15, kg = lane >> 4;
    int lr = lane >> 3, lc = lane & 7;
    int swz = (lc ^ (lr & 7)) * 8;
    __shared__ ushort Kt[2][64 * 64];
    __shared__ ushort Vt[2][64 * 64];
    __shared__ ushort Pl[4][16 * 64];
    const ushort* qh = qb + (long)h * N_TOK * 64;
    const ushort* kh = kb + (long)h * N_TOK * 64;
    const ushort* vh = vT + (long)h * 64 * N_TOK;
    int q0 = qt * 64 + w * 16;
    bf16x8 qf0 = *(const bf16x8*)(qh + (long)(q0 + fr) * 64 + kg * 8);
    bf16x8 qf1 = *(const bf16x8*)(qh + (long)(q0 + fr) * 64 + 32 + kg * 8);
    f32x4 o[4] = {};
    float mrun = -1e30f, lrun = 0.f;  // per-lane stats for q = q0 + fr
    int nbase = cz * (N_TOK / NC_ATT);
    auto stage = [&](int buf, int s) {
        int n0 = nbase + s * 64;
#pragma unroll
        for (int j = 0; j < 2; ++j) {
            int i = w * 2 + j;
            int row = i * 8 + lr;
            __builtin_amdgcn_global_load_lds(
                (const __attribute__((address_space(1))) unsigned int*)(kh + (long)(n0 + row) * 64 + swz),
                (__attribute__((address_space(3))) unsigned int*)(&Kt[buf][i * 512]), 16, 0, 0);
        }
#pragma unroll
        for (int j = 0; j < 2; ++j) {
            int i = w * 2 + j;
            int row = i * 8 + lr;
            __builtin_amdgcn_global_load_lds(
                (const __attribute__((address_space(1))) unsigned int*)(vh + (long)row * N_TOK + n0 + swz),
                (__attribute__((address_space(3))) unsigned int*)(&Vt[buf][i * 512]), 16, 0, 0);
        }
    };
    stage(0, 0);
    __syncthreads();
    const int NS = (N_TOK / NC_ATT) / 64;
    for (int s = 0; s < NS; ++s) {
        int buf = s & 1;
        if (s + 1 < NS) stage(buf ^ 1, s + 1);
        // S^T = K @ Q^T: lane holds kv = t*16+kg*4+r for q = q0+fr
        f32x4 sc[4] = {};
#pragma unroll
        for (int t = 0; t < 4; ++t) {
            int row = t * 16 + fr;
            bf16x8 k0 = *(const bf16x8*)(&Kt[buf][row * 64 + ((kg * 8) ^ ((row & 7) * 8))]);
            bf16x8 k1 = *(const bf16x8*)(&Kt[buf][row * 64 + ((32 + kg * 8) ^ ((row & 7) * 8))]);
            sc[t] = __builtin_amdgcn_mfma_f32_16x16x32_bf16(k0, qf0, sc[t], 0, 0, 0);
            sc[t] = __builtin_amdgcn_mfma_f32_16x16x32_bf16(k1, qf1, sc[t], 0, 0, 0);
        }
        float mx = sc[0][0];
#pragma unroll
        for (int t = 0; t < 4; ++t)
#pragma unroll
            for (int r = 0; r < 4; ++r) mx = fmaxf(mx, sc[t][r]);
        mx = fmaxf(mx, __shfl_xor(mx, 16));
        mx = fmaxf(mx, __shfl_xor(mx, 32));
        float mnew = fmaxf(mrun, mx);
        float alpha = __expf(mrun - mnew);
        float rs = 0.f;
#pragma unroll
        for (int t = 0; t < 4; ++t)
#pragma unroll
            for (int r = 0; r < 4; ++r) {
                float p = __expf(sc[t][r] - mnew);
                sc[t][r] = p;
                rs += p;
            }
        rs += __shfl_xor(rs, 16);
        rs += __shfl_xor(rs, 32);
        lrun = lrun * alpha + rs;
        mrun = mnew;
        float aq[4];
#pragma unroll
        for (int r = 0; r < 4; ++r) aq[r] = __shfl(alpha, kg * 4 + r);
#pragma unroll
        for (int t = 0; t < 4; ++t)
#pragma unroll
            for (int r = 0; r < 4; ++r) o[t][r] *= aq[r];
        // P[q=fr][kv]: pack 4 consecutive kv per tile -> b64 write
#pragma unroll
        for (int t = 0; t < 4; ++t) {
            uint2 u;
            u.x = pkbf(sc[t][0], sc[t][1]);
            u.y = pkbf(sc[t][2], sc[t][3]);
            *(uint2*)(&Pl[w][fr * 64 + ((t * 16 + kg * 4) ^ ((fr & 7) * 8))]) = u;
        }
#pragma unroll
        for (int ks = 0; ks < 2; ++ks) {
            bf16x8 pf = *(const bf16x8*)(&Pl[w][fr * 64 + ((ks * 32 + kg * 8) ^ ((fr & 7) * 8))]);
#pragma unroll
            for (int t = 0; t < 4; ++t) {
                int row = t * 16 + fr;
                bf16x8 b = *(const bf16x8*)(&Vt[buf][row * 64 + ((ks * 32 + kg * 8) ^ ((row & 7) * 8))]);
                o[t] = __builtin_amdgcn_mfma_f32_16x16x32_bf16(pf, b, o[t], 0, 0, 0);
            }
        }
        __syncthreads();
    }
    float linv = 1.0f / lrun;
    float lq[4];
#pragma unroll
    for (int r = 0; r < 4; ++r) lq[r] = __shfl(linv, kg * 4 + r);
    float* ob = opart + (((long)cz * 4 + h) * N_TOK + q0 + kg * 4) * 64;
#pragma unroll
    for (int t = 0; t < 4; ++t)
#pragma unroll
        for (int r = 0; r < 4; ++r)
            ob[(long)r * 64 + t * 16 + fr] = o[t][r] * lq[r];
    if (lane < 16) {
        float* mlb = mlpart + (((long)cz * 4 + h) * N_TOK + q0 + lane) * 2;
        mlb[0] = mrun;
        mlb[1] = lrun;
    }
}

// ---------------- combine KV-chunk partials -> mho row-major [4096][256] ----
__global__ __launch_bounds__(256) void attn_combine(
    const float* __restrict__ opart, const float* __restrict__ mlpart,
    ushort* __restrict__ mho) {
    int h = blockIdx.y;
    int q0 = blockIdx.x * 64;
    int tid = threadIdx.x;
    int ql = tid >> 4, qv = tid & 15;
#pragma unroll
    for (int pass = 0; pass < 4; ++pass) {
        int q = q0 + pass * 16 + ql;
        float m[NC_ATT], l[NC_ATT], M = -1e30f;
#pragma unroll
        for (int c = 0; c < NC_ATT; ++c) {
            const float* mlb = mlpart + (((long)c * 4 + h) * N_TOK + q) * 2;
            m[c] = mlb[0]; l[c] = mlb[1];
            M = fmaxf(M, m[c]);
        }
        float L = 0.f, wgt[NC_ATT];
#pragma unroll
        for (int c = 0; c < NC_ATT; ++c) { wgt[c] = __expf(m[c] - M); L += l[c] * wgt[c]; }
        float inv = 1.0f / L;
#pragma unroll
        for (int c = 0; c < NC_ATT; ++c) wgt[c] *= l[c] * inv;
        float ax = 0.f, ay = 0.f, az = 0.f, aw = 0.f;
#pragma unroll
        for (int c = 0; c < NC_ATT; ++c) {
            float4 v = *(const float4*)(opart + (((long)c * 4 + h) * N_TOK + q) * 64 + qv * 4);
            ax += v.x * wgt[c]; ay += v.y * wgt[c]; az += v.z * wgt[c]; aw += v.w * wgt[c];
        }
        ushort4 o;
        o.x = f2bf(ax); o.y = f2bf(ay); o.z = f2bf(az); o.w = f2bf(aw);
        *(ushort4*)(mho + (long)q * 256 + h * 64 + qv * 4) = o;
    }
}

// ---------------- generic gemm_bt: C = A @ BT^T (bf16 out) ------------------
__global__ __launch_bounds__(256) void gemm_bt_plain(
    const ushort* __restrict__ A, const ushort* __restrict__ BT,
    ushort* __restrict__ outp, int Ncols, int Kd) {
    int m0 = blockIdx.x * 64, n0 = blockIdx.y * 64;
    int wave = threadIdx.x >> 6, lane = threadIdx.x & 63;
    int fr = lane & 15, kg = lane >> 4;
    int wm = m0 + wave * 16;
    f32x4 acc[4] = {};
    for (int k0 = 0; k0 < Kd; k0 += 32) {
        bf16x8 a = *(const bf16x8*)(A + (long)(wm + fr) * Kd + k0 + kg * 8);
#pragma unroll
        for (int t = 0; t < 4; ++t) {
            bf16x8 b = *(const bf16x8*)(BT + (long)(n0 + t * 16 + fr) * Kd + k0 + kg * 8);
            acc[t] = __builtin_amdgcn_mfma_f32_16x16x32_bf16(a, b, acc[t], 0, 0, 0);
        }
    }
    int rb = wm + kg * 4;
#pragma unroll
    for (int t = 0; t < 4; ++t) {
        int col = n0 + t * 16 + fr;
#pragma unroll
        for (int r = 0; r < 4; ++r)
            outp[(long)(rb + r) * Ncols + col] = f2bf(acc[t][r]);
    }
}

// ---------------- fused: part[c] = (sum_f w_f*rpe[f] + b)[.,Kc] @ PT^T ------
// PT = (mho @ Wo)^T bf16 [128][4096]. N=128. T14: A-loads early, LDS-write late.
__global__ __launch_bounds__(512) void gemm_big_fused(
    const float* __restrict__ rpe, const float* __restrict__ rpe_w,
    const float* __restrict__ rpe_b, const ushort* __restrict__ PT,
    float* __restrict__ part) {
    int mt = blockIdx.x, cz = blockIdx.y;
    int tid = threadIdx.x;
    int w = tid >> 6, lane = tid & 63;
    int fr = lane & 15, kg = lane >> 4;
    int lr = lane >> 3, lc = lane & 7;
    int swz = (lc ^ (lr & 7)) * 8;
    int ms = w >> 1, nh = w & 1;
    __shared__ ushort Bt[2][128 * 64];
    __shared__ ushort At[2][64 * 64];
    int m0 = mt * 64;
    long kbase = (long)cz * (N_TOK / NC_GEMM);
    float w0 = rpe_w[0], w1 = rpe_w[1], w2 = rpe_w[2], w3 = rpe_w[3], w4 = rpe_w[4];
    float bb = rpe_b[0];
    auto stage_B = [&](int buf, int s) {
        const ushort* src = PT + kbase + s * 64 + swz;
#pragma unroll
        for (int j = 0; j < 2; ++j) {
            int i = w * 2 + j;
            int row = i * 8 + lr;
            __builtin_amdgcn_global_load_lds(
                (const __attribute__((address_space(1))) unsigned int*)(src + (long)row * N_TOK),
                (__attribute__((address_space(3))) unsigned int*)(&Bt[buf][i * 512]), 16, 0, 0);
        }
    };
    float4 pA[10];  // 2 rounds x 5 planes, statically indexed
    auto load_A = [&](int s) {
        const float* base = rpe + (long)m0 * N_TOK + kbase + s * 64;
#pragma unroll
        for (int rnd = 0; rnd < 2; ++rnd) {
            int idx = tid + rnd * 512;
            int row = idx >> 4, c4 = (idx & 15) * 4;
            const float* pr = base + (long)row * N_TOK + c4;
#pragma unroll
            for (int pl = 0; pl < 5; ++pl)
                pA[rnd * 5 + pl] = *(const float4*)(pr + (long)pl * ((long)N_TOK * N_TOK));
        }
    };
    auto write_A = [&](int buf) {
#pragma unroll
        for (int rnd = 0; rnd < 2; ++rnd) {
            int idx = tid + rnd * 512;
            int row = idx >> 4, c4 = (idx & 15) * 4;
            float4 p0 = pA[rnd * 5], p1 = pA[rnd * 5 + 1], p2 = pA[rnd * 5 + 2];
            float4 p3 = pA[rnd * 5 + 3], p4 = pA[rnd * 5 + 4];
            float v0 = bb + w0 * p0.x + w1 * p1.x + w2 * p2.x + w3 * p3.x + w4 * p4.x;
            float v1 = bb + w0 * p0.y + w1 * p1.y + w2 * p2.y + w3 * p3.y + w4 * p4.y;
            float v2 = bb + w0 * p0.z + w1 * p1.z + w2 * p2.z + w3 * p3.z + w4 * p4.z;
            float v3 = bb + w0 * p0.w + w1 * p1.w + w2 * p2.w + w3 * p3.w + w4 * p4.w;
            uint2 u;
            u.x = pkbf(v0, v1);
            u.y = pkbf(v2, v3);
            *(uint2*)(&At[buf][row * 64 + (c4 ^ ((row & 7) * 8))]) = u;
        }
    };
    f32x4 acc[4] = {};
    load_A(0);
    stage_B(0, 0);
    write_A(0);
    __syncthreads();
    const int NS = (N_TOK / NC_GEMM) / 64;
    int arow = ms * 16 + fr;
    for (int s = 0; s < NS; ++s) {
        int buf = s & 1;
        if (s + 1 < NS) { stage_B(buf ^ 1, s + 1); load_A(s + 1); }
#pragma unroll
        for (int ks = 0; ks < 2; ++ks) {
            bf16x8 av = *(const bf16x8*)(&At[buf][arow * 64 + ((ks * 32 + kg * 8) ^ ((arow & 7) * 8))]);
#pragma unroll
            for (int nf = 0; nf < 4; ++nf) {
                int row = nh * 64 + nf * 16 + fr;
                bf16x8 b = *(const bf16x8*)(&Bt[buf][row * 64 + ((ks * 32 + kg * 8) ^ ((row & 7) * 8))]);
                acc[nf] = __builtin_amdgcn_mfma_f32_16x16x32_bf16(av, b, acc[nf], 0, 0, 0);
            }
        }
        if (s + 1 < NS) write_A(buf ^ 1);  // vmcnt wait lands AFTER the MFMAs
        __syncthreads();
    }
    float* pb = part + ((long)cz * N_TOK + m0 + ms * 16 + kg * 4) * 128 + nh * 64 + fr;
#pragma unroll
    for (int nf = 0; nf < 4; ++nf)
#pragma unroll
        for (int r = 0; r < 4; ++r)
            pb[(long)r * 128 + nf * 16] = acc[nf][r];
}

// ---------------- megatail: sum parts + bo + x -> LN1 -> FFN -> LN2 -> out --
__global__ __launch_bounds__(256) void megatail(
    const float* __restrict__ gpart, const float* __restrict__ bo,
    const float* __restrict__ x, const float* __restrict__ g1,
    const float* __restrict__ lb1, const ushort* __restrict__ W1T,
    const float* __restrict__ b1, const ushort* __restrict__ W2T,
    const float* __restrict__ b2, const float* __restrict__ g2,
    const float* __restrict__ lb2, float* __restrict__ out) {
    int r0 = blockIdx.x * 16;
    int tid = threadIdx.x;
    int w = tid >> 6, lane = tid & 63;
    int fr = lane & 15, kg = lane >> 4;
    __shared__ float x1f[16][132];
    __shared__ ushort x1b[16][128];
    __shared__ ushort hbuf[16][256];
    __shared__ float otile[16][132];
    int row = tid >> 4, c0 = (tid & 15) * 8;
    // phase 0: v = sum_c gpart[c] + bo + x, then LN1 (all in-register per row)
    {
        float v[8];
        float4 s0 = {0.f, 0.f, 0.f, 0.f}, s1 = {0.f, 0.f, 0.f, 0.f};
#pragma unroll
        for (int c = 0; c < NC_GEMM; ++c) {
            const float* pr = gpart + ((long)c * N_TOK + r0 + row) * 128 + c0;
            float4 a = *(const float4*)(pr);
            float4 b = *(const float4*)(pr + 4);
            s0.x += a.x; s0.y += a.y; s0.z += a.z; s0.w += a.w;
            s1.x += b.x; s1.y += b.y; s1.z += b.z; s1.w += b.w;
        }
        const float* xr = x + (long)(r0 + row) * 128 + c0;
        v[0] = s0.x + bo[c0 + 0] + xr[0];
        v[1] = s0.y + bo[c0 + 1] + xr[1];
        v[2] = s0.z + bo[c0 + 2] + xr[2];
        v[3] = s0.w + bo[c0 + 3] + xr[3];
        v[4] = s1.x + bo[c0 + 4] + xr[4];
        v[5] = s1.y + bo[c0 + 5] + xr[5];
        v[6] = s1.z + bo[c0 + 6] + xr[6];
        v[7] = s1.w + bo[c0 + 7] + xr[7];
        float s = 0.f;
#pragma unroll
        for (int jj = 0; jj < 8; ++jj) s += v[jj];
#pragma unroll
        for (int off = 1; off < 16; off <<= 1) s += __shfl_xor(s, off);
        float mean = s * (1.0f / 128.0f);
        float ss = 0.f;
#pragma unroll
        for (int jj = 0; jj < 8; ++jj) { float d = v[jj] - mean; ss += d * d; }
#pragma unroll
        for (int off = 1; off < 16; off <<= 1) ss += __shfl_xor(ss, off);
        float rstd = rsqrtf(ss * (1.0f / 128.0f) + 1e-5f);
        union { bf16x8 vec; ushort us[8]; } pk8;
#pragma unroll
        for (int jj = 0; jj < 8; ++jj) {
            float y = (v[jj] - mean) * rstd * g1[c0 + jj] + lb1[c0 + jj];
            x1f[row][c0 + jj] = y;
            pk8.us[jj] = f2bf(y);
        }
        *(bf16x8*)(&x1b[row][c0 ^ ((row & 7) * 8)]) = pk8.vec;
    }
    __syncthreads();
    // phase 1: h = relu(x1b @ W1T^T + b1)  (wave w -> cols w*64..w*64+63)
    {
        f32x4 a1[4] = {};
#pragma unroll
        for (int ks = 0; ks < 4; ++ks) {
            bf16x8 a = *(const bf16x8*)(&x1b[fr][(ks * 32 + kg * 8) ^ ((fr & 7) * 8)]);
#pragma unroll
            for (int t = 0; t < 4; ++t) {
                bf16x8 b = *(const bf16x8*)(W1T + (long)(w * 64 + t * 16 + fr) * 128 + ks * 32 + kg * 8);
                a1[t] = __builtin_amdgcn_mfma_f32_16x16x32_bf16(a, b, a1[t], 0, 0, 0);
            }
        }
#pragma unroll
        for (int t = 0; t < 4; ++t) {
            int col = w * 64 + t * 16 + fr;
            float bs = b1[col];
#pragma unroll
            for (int r = 0; r < 4; ++r) {
                int rr = kg * 4 + r;
                hbuf[rr][col ^ ((rr & 7) * 8)] = f2bf(fmaxf(a1[t][r] + bs, 0.f));
            }
        }
    }
    __syncthreads();
    // phase 2: o = h @ W2T^T + b2 + x1  (wave w -> cols w*32..w*32+31)
    {
        f32x4 a2[2] = {};
#pragma unroll
        for (int ks = 0; ks < 8; ++ks) {
            bf16x8 a = *(const bf16x8*)(&hbuf[fr][(ks * 32 + kg * 8) ^ ((fr & 7) * 8)]);
#pragma unroll
            for (int t = 0; t < 2; ++t) {
                bf16x8 b = *(const bf16x8*)(W2T + (long)(w * 32 + t * 16 + fr) * 256 + ks * 32 + kg * 8);
                a2[t] = __builtin_amdgcn_mfma_f32_16x16x32_bf16(a, b, a2[t], 0, 0, 0);
            }
        }
#pragma unroll
        for (int t = 0; t < 2; ++t) {
            int col = w * 32 + t * 16 + fr;
            float bs = b2[col];
#pragma unroll
            for (int r = 0; r < 4; ++r) {
                int rr = kg * 4 + r;
                otile[rr][col] = a2[t][r] + bs + x1f[rr][col];
            }
        }
    }
    __syncthreads();
    // phase 2b: LN2 -> out fp32
    {
        float v[8];
        float s = 0.f;
#pragma unroll
        for (int jj = 0; jj < 8; ++jj) { v[jj] = otile[row][c0 + jj]; s += v[jj]; }
#pragma unroll
        for (int off = 1; off < 16; off <<= 1) s += __shfl_xor(s, off);
        float mean = s * (1.0f / 128.0f);
        float ss = 0.f;
#pragma unroll
        for (int jj = 0; jj < 8; ++jj) { float d = v[jj] - mean; ss += d * d; }
#pragma unroll
        for (int off = 1; off < 16; off <<= 1) ss += __shfl_xor(ss, off);
        float rstd = rsqrtf(ss * (1.0f / 128.0f) + 1e-5f);
#pragma unroll
        for (int jj = 0; jj < 8; ++jj) {
            float y = (v[jj] - mean) * rstd * g2[c0 + jj] + lb2[c0 + jj];
            out[(long)(r0 + row) * 128 + c0 + jj] = y;
        }
    }
}

extern "C" void kernel_launch(void* const* d_in, const int* in_sizes, int n_in,
                              void* d_out, int out_size, void* d_ws, size_t ws_size,
                              hipStream_t stream) {
    const float* x     = (const float*)d_in[0];
    const float* rpe   = (const float*)d_in[1];
    const float* Wq    = (const float*)d_in[2];
    const float* bq    = (const float*)d_in[3];
    const float* Wk    = (const float*)d_in[4];
    const float* bk    = (const float*)d_in[5];
    const float* Wv    = (const float*)d_in[6];
    const float* bv    = (const float*)d_in[7];
    const float* rpe_w = (const float*)d_in[8];
    const float* rpe_b = (const float*)d_in[9];
    const float* Wo    = (const float*)d_in[10];
    const float* bo    = (const float*)d_in[11];
    const float* W1    = (const float*)d_in[12];
    const float* b1    = (const float*)d_in[13];
    const float* W2    = (const float*)d_in[14];
    const float* b2    = (const float*)d_in[15];
    const float* g1    = (const float*)d_in[16];
    const float* lb1   = (const float*)d_in[17];
    const float* g2    = (const float*)d_in[18];
    const float* lb2   = (const float*)d_in[19];

    char* wp = (char*)d_ws;
    auto alloc = [&](size_t sz) { char* p = wp; wp += (sz + 255) & ~(size_t)255; return p; };
    ushort* xb    = (ushort*)alloc((size_t)4096 * 128 * 2);
    ushort* WqT   = (ushort*)alloc((size_t)4 * 64 * 128 * 2);
    ushort* WkT   = (ushort*)alloc((size_t)4 * 64 * 128 * 2);
    ushort* WvT   = (ushort*)alloc((size_t)4 * 64 * 128 * 2);
    ushort* WoT   = (ushort*)alloc((size_t)128 * 256 * 2);
    ushort* W1T   = (ushort*)alloc((size_t)256 * 128 * 2);
    ushort* W2T   = (ushort*)alloc((size_t)128 * 256 * 2);
    ushort* qb    = (ushort*)alloc((size_t)4 * 4096 * 64 * 2);
    ushort* kbuf  = (ushort*)alloc((size_t)4 * 4096 * 64 * 2);
    ushort* vT    = (ushort*)alloc((size_t)4 * 64 * 4096 * 2);
    ushort* mho   = (ushort*)alloc((size_t)4096 * 256 * 2);
    ushort* PTb   = (ushort*)alloc((size_t)128 * 4096 * 2);
    float*  opart = (float*)alloc((size_t)NC_ATT * 4 * 4096 * 64 * 4);
    float*  mlprt = (float*)alloc((size_t)NC_ATT * 4 * 4096 * 2 * 4);
    float*  gpart = (float*)alloc((size_t)NC_GEMM * 4096 * 128 * 4);

    prep_all<<<1280, 256, 0, stream>>>(x, Wq, Wk, Wv, Wo, W1, W2,
                                       xb, WqT, WkT, WvT, WoT, W1T, W2T);
    qkv_proj<<<dim3(64, 12), 256, 0, stream>>>(xb, WqT, WkT, WvT, bq, bk, bv, qb, kbuf, vT);
    attn_flash2<<<dim3(64, 4, NC_ATT), 256, 0, stream>>>(qb, kbuf, vT, opart, mlprt);
    attn_combine<<<dim3(64, 4), 256, 0, stream>>>(opart, mlprt, mho);
    gemm_bt_plain<<<dim3(2, 64), 256, 0, stream>>>(WoT, mho, PTb, 4096, 256);
    gemm_big_fused<<<dim3(64, NC_GEMM), 512, 0, stream>>>(rpe, rpe_w, rpe_b, PTb, gpart);
    megatail<<<256, 256, 0, stream>>>(gpart, bo, x, g1, lb1, W1T, b1, W2T, b2,
                                      g2, lb2, (float*)d_out);
}

// Round 6
// 151.571 us; speedup vs baseline: 2.5637x; 1.0057x over previous
//
#include <hip/hip_runtime.h>

typedef __attribute__((ext_vector_type(8))) short bf16x8;
typedef __attribute__((ext_vector_type(4))) float f32x4;

#define N_TOK 4096
#define NC_ATT 4
#define NC_GEMM 8

static __device__ __forceinline__ ushort f2bf(float f) {
    union { float f; unsigned u; } x; x.f = f;
    unsigned u = x.u;
    unsigned r = (u + 0x7FFFu + ((u >> 16) & 1u)) >> 16;
    return (ushort)r;
}
static __device__ __forceinline__ unsigned pkbf(float a, float b) {
    return (unsigned)f2bf(a) | ((unsigned)f2bf(b) << 16);
}
static __device__ __forceinline__ float bf2f(ushort u) {
    union { unsigned u; float f; } x; x.u = (unsigned)u << 16; return x.f;
}

// ---------------- prep: cast x + all weight transposes in one kernel ------
__global__ void prep_all(const float* __restrict__ x,
                         const float* __restrict__ Wq, const float* __restrict__ Wk,
                         const float* __restrict__ Wv, const float* __restrict__ Wo,
                         const float* __restrict__ W1, const float* __restrict__ W2,
                         ushort* __restrict__ xb, ushort* __restrict__ WqT,
                         ushort* __restrict__ WkT, ushort* __restrict__ WvT,
                         ushort* __restrict__ WoT, ushort* __restrict__ W1T,
                         ushort* __restrict__ W2T) {
    int i = blockIdx.x * 256 + threadIdx.x;
    if (i < 131072) {  // x: 4096*128/4 quads
        float4 v = ((const float4*)x)[i];
        ushort4 o;
        o.x = f2bf(v.x); o.y = f2bf(v.y); o.z = f2bf(v.z); o.w = f2bf(v.w);
        ((ushort4*)xb)[i] = o;
        return;
    }
    int j = i - 131072;
    int t = j >> 15, e = j & 32767;
    if (t < 3) {  // Wq/Wk/Wv [4][128][64] -> [4][64][128]
        const float* src = (t == 0 ? Wq : t == 1 ? Wk : Wv);
        ushort* dst = (t == 0 ? WqT : t == 1 ? WkT : WvT);
        int h = e >> 13, rem = e & 8191, d = rem >> 6, k = rem & 63;
        dst[h * 8192 + k * 128 + d] = f2bf(src[e]);
    } else if (t == 3) {  // Wo [256][128] -> [128][256]
        int r = e >> 7, c = e & 127;
        WoT[c * 256 + r] = f2bf(Wo[e]);
    } else if (t == 4) {  // W1 [128][256] -> [256][128]
        int r = e >> 8, c = e & 255;
        W1T[c * 128 + r] = f2bf(W1[e]);
    } else {  // W2 [256][128] -> [128][256]
        int r = e >> 7, c = e & 127;
        W2T[c * 256 + r] = f2bf(W2[e]);
    }
}

// ---------------- QKV projection: relu(xb @ W^T + b) ------------------------
// q pre-scaled by 0.125*log2(e) so attention works in exp2 domain.
__global__ __launch_bounds__(256) void qkv_proj(
    const ushort* __restrict__ xb, const ushort* __restrict__ WqT,
    const ushort* __restrict__ WkT, const ushort* __restrict__ WvT,
    const float* __restrict__ bq, const float* __restrict__ bk, const float* __restrict__ bv,
    ushort* __restrict__ qb, ushort* __restrict__ kb, ushort* __restrict__ vT) {
    int m0 = blockIdx.x * 64;
    int h = blockIdx.y & 3, which = blockIdx.y >> 2;
    int wave = threadIdx.x >> 6, lane = threadIdx.x & 63;
    int fr = lane & 15, kg = lane >> 4;
    int wm = m0 + wave * 16;
    const ushort* WT = (which == 0 ? WqT : which == 1 ? WkT : WvT) + (long)h * 64 * 128;
    const float* bias = (which == 0 ? bq : which == 1 ? bk : bv) + h * 64;
    f32x4 acc[4] = {};
    for (int k0 = 0; k0 < 128; k0 += 32) {
        bf16x8 a = *(const bf16x8*)(xb + (long)(wm + fr) * 128 + k0 + kg * 8);
#pragma unroll
        for (int t = 0; t < 4; ++t) {
            bf16x8 b = *(const bf16x8*)(WT + (long)(t * 16 + fr) * 128 + k0 + kg * 8);
            acc[t] = __builtin_amdgcn_mfma_f32_16x16x32_bf16(a, b, acc[t], 0, 0, 0);
        }
    }
    int rb = wm + kg * 4;
#pragma unroll
    for (int t = 0; t < 4; ++t) {
        int col = t * 16 + fr;
        float bs = bias[col];
        if (which == 2) {
            ushort4 o;
            o.x = f2bf(fmaxf(acc[t][0] + bs, 0.f));
            o.y = f2bf(fmaxf(acc[t][1] + bs, 0.f));
            o.z = f2bf(fmaxf(acc[t][2] + bs, 0.f));
            o.w = f2bf(fmaxf(acc[t][3] + bs, 0.f));
            *(ushort4*)(vT + ((long)h * 64 + col) * N_TOK + rb) = o;
        } else {
            ushort* dst = (which == 0 ? qb : kb) + (long)h * N_TOK * 64;
            float scl = (which == 0) ? 0.125f * 1.44269504f : 1.0f;
#pragma unroll
            for (int r = 0; r < 4; ++r)
                dst[(long)(rb + r) * 64 + col] = f2bf(fmaxf(acc[t][r] + bs, 0.f) * scl);
        }
    }
}

// ---------------- flash attention: swapped QK^T, exp2 domain, defer-max -----
__global__ __launch_bounds__(256) void attn_flash2(
    const ushort* __restrict__ qb, const ushort* __restrict__ kb,
    const ushort* __restrict__ vT, ushort* __restrict__ opart,
    float* __restrict__ mlpart) {
    int qt = blockIdx.x, h = blockIdx.y, cz = blockIdx.z;
    int w = threadIdx.x >> 6, lane = threadIdx.x & 63;
    int fr = lane & 15, kg = lane >> 4;
    int lr = lane >> 3, lc = lane & 7;
    int swz = (lc ^ (lr & 7)) * 8;
    __shared__ ushort Kt[2][64 * 64];
    __shared__ ushort Vt[2][64 * 64];
    __shared__ ushort Pl[4][16 * 64];
    const ushort* qh = qb + (long)h * N_TOK * 64;
    const ushort* kh = kb + (long)h * N_TOK * 64;
    const ushort* vh = vT + (long)h * 64 * N_TOK;
    int q0 = qt * 64 + w * 16;
    bf16x8 qf0 = *(const bf16x8*)(qh + (long)(q0 + fr) * 64 + kg * 8);
    bf16x8 qf1 = *(const bf16x8*)(qh + (long)(q0 + fr) * 64 + 32 + kg * 8);
    f32x4 o[4] = {};
    float mrun = -1e30f, lrun = 0.f;  // per-lane stats for q = q0 + fr (log2 dom)
    int nbase = cz * (N_TOK / NC_ATT);
    auto stage = [&](int buf, int s) {
        int n0 = nbase + s * 64;
#pragma unroll
        for (int j = 0; j < 2; ++j) {
            int i = w * 2 + j;
            int row = i * 8 + lr;
            __builtin_amdgcn_global_load_lds(
                (const __attribute__((address_space(1))) unsigned int*)(kh + (long)(n0 + row) * 64 + swz),
                (__attribute__((address_space(3))) unsigned int*)(&Kt[buf][i * 512]), 16, 0, 0);
        }
#pragma unroll
        for (int j = 0; j < 2; ++j) {
            int i = w * 2 + j;
            int row = i * 8 + lr;
            __builtin_amdgcn_global_load_lds(
                (const __attribute__((address_space(1))) unsigned int*)(vh + (long)row * N_TOK + n0 + swz),
                (__attribute__((address_space(3))) unsigned int*)(&Vt[buf][i * 512]), 16, 0, 0);
        }
    };
    stage(0, 0);
    __syncthreads();
    const int NS = (N_TOK / NC_ATT) / 64;
    for (int s = 0; s < NS; ++s) {
        int buf = s & 1;
        if (s + 1 < NS) stage(buf ^ 1, s + 1);
        // S^T = K @ Q^T: lane holds kv = t*16+kg*4+r for q = q0+fr
        f32x4 sc[4] = {};
#pragma unroll
        for (int t = 0; t < 4; ++t) {
            int row = t * 16 + fr;
            bf16x8 k0 = *(const bf16x8*)(&Kt[buf][row * 64 + ((kg * 8) ^ ((row & 7) * 8))]);
            bf16x8 k1 = *(const bf16x8*)(&Kt[buf][row * 64 + ((32 + kg * 8) ^ ((row & 7) * 8))]);
            sc[t] = __builtin_amdgcn_mfma_f32_16x16x32_bf16(k0, qf0, sc[t], 0, 0, 0);
            sc[t] = __builtin_amdgcn_mfma_f32_16x16x32_bf16(k1, qf1, sc[t], 0, 0, 0);
        }
        float mx = sc[0][0];
#pragma unroll
        for (int t = 0; t < 4; ++t)
#pragma unroll
            for (int r = 0; r < 4; ++r) mx = fmaxf(mx, sc[t][r]);
        mx = fmaxf(mx, __shfl_xor(mx, 16));
        mx = fmaxf(mx, __shfl_xor(mx, 32));
        // defer-max: only rescale when tile max grew past threshold (log2 units)
        if (__any(mx - mrun > 8.f)) {
            float mnew = fmaxf(mrun, mx);
            float alpha = exp2f(mrun - mnew);
            lrun *= alpha;
            mrun = mnew;
            float aq[4];
#pragma unroll
            for (int r = 0; r < 4; ++r) aq[r] = __shfl(alpha, kg * 4 + r);
#pragma unroll
            for (int t = 0; t < 4; ++t)
#pragma unroll
                for (int r = 0; r < 4; ++r) o[t][r] *= aq[r];
        }
        float rs = 0.f;
#pragma unroll
        for (int t = 0; t < 4; ++t)
#pragma unroll
            for (int r = 0; r < 4; ++r) {
                float p = exp2f(sc[t][r] - mrun);
                sc[t][r] = p;
                rs += p;
            }
        rs += __shfl_xor(rs, 16);
        rs += __shfl_xor(rs, 32);
        lrun += rs;
        // P[q=fr][kv]: pack 4 consecutive kv per tile -> b64 write
#pragma unroll
        for (int t = 0; t < 4; ++t) {
            uint2 u;
            u.x = pkbf(sc[t][0], sc[t][1]);
            u.y = pkbf(sc[t][2], sc[t][3]);
            *(uint2*)(&Pl[w][fr * 64 + ((t * 16 + kg * 4) ^ ((fr & 7) * 8))]) = u;
        }
#pragma unroll
        for (int ks = 0; ks < 2; ++ks) {
            bf16x8 pf = *(const bf16x8*)(&Pl[w][fr * 64 + ((ks * 32 + kg * 8) ^ ((fr & 7) * 8))]);
#pragma unroll
            for (int t = 0; t < 4; ++t) {
                int row = t * 16 + fr;
                bf16x8 b = *(const bf16x8*)(&Vt[buf][row * 64 + ((ks * 32 + kg * 8) ^ ((row & 7) * 8))]);
                o[t] = __builtin_amdgcn_mfma_f32_16x16x32_bf16(pf, b, o[t], 0, 0, 0);
            }
        }
        __syncthreads();
    }
    float linv = 1.0f / lrun;
    float lq[4];
#pragma unroll
    for (int r = 0; r < 4; ++r) lq[r] = __shfl(linv, kg * 4 + r);
    ushort* ob = opart + (((long)cz * 4 + h) * N_TOK + q0 + kg * 4) * 64;
#pragma unroll
    for (int t = 0; t < 4; ++t)
#pragma unroll
        for (int r = 0; r < 4; ++r)
            ob[(long)r * 64 + t * 16 + fr] = f2bf(o[t][r] * lq[r]);
    if (lane < 16) {
        float* mlb = mlpart + (((long)cz * 4 + h) * N_TOK + q0 + lane) * 2;
        mlb[0] = mrun;
        mlb[1] = lrun;
    }
}

// ---------------- combine KV-chunks + Wo-projection -> PT bf16 [128][4096] --
// Phase A: mho tile [64 q][256 c] built in LDS (XOR swizzle).
// Phase B: PT[:, qtile] = WoT @ mho_tile^T via MFMA.
__global__ __launch_bounds__(256) void combine_wo(
    const ushort* __restrict__ opart, const float* __restrict__ mlpart,
    const ushort* __restrict__ WoT, ushort* __restrict__ PT) {
    int q0 = blockIdx.x * 64;
    int tid = threadIdx.x;
    __shared__ ushort mt[64 * 256];
    {
        int q = tid >> 2, vg = tid & 3;
        long qg = q0 + q;
#pragma unroll
        for (int h = 0; h < 4; ++h) {
            float m[NC_ATT], l[NC_ATT], M = -1e30f;
#pragma unroll
            for (int c = 0; c < NC_ATT; ++c) {
                const float* mlb = mlpart + (((long)c * 4 + h) * N_TOK + qg) * 2;
                m[c] = mlb[0]; l[c] = mlb[1];
                M = fmaxf(M, m[c]);
            }
            float L = 0.f, co[NC_ATT];
#pragma unroll
            for (int c = 0; c < NC_ATT; ++c) { co[c] = exp2f(m[c] - M) * l[c]; L += co[c]; }
            float inv = 1.0f / L;
#pragma unroll
            for (int c = 0; c < NC_ATT; ++c) co[c] *= inv;
            float a[16];
#pragma unroll
            for (int j = 0; j < 16; ++j) a[j] = 0.f;
#pragma unroll
            for (int c = 0; c < NC_ATT; ++c) {
                const ushort* pr = opart + (((long)c * 4 + h) * N_TOK + qg) * 64 + vg * 16;
                bf16x8 v0 = *(const bf16x8*)(pr);
                bf16x8 v1 = *(const bf16x8*)(pr + 8);
#pragma unroll
                for (int j = 0; j < 8; ++j) {
                    a[j] += co[c] * bf2f((ushort)v0[j]);
                    a[8 + j] += co[c] * bf2f((ushort)v1[j]);
                }
            }
            int c0 = h * 64 + vg * 16;
            uint2 u0, u1;
            u0.x = pkbf(a[0], a[1]); u0.y = pkbf(a[2], a[3]);
            u1.x = pkbf(a[4], a[5]); u1.y = pkbf(a[6], a[7]);
            *(uint2*)(&mt[q * 256 + (c0 ^ ((q & 7) * 8))]) = u0;
            *(uint2*)(&mt[q * 256 + ((c0 + 4) ^ ((q & 7) * 8))]) = u1;
            u0.x = pkbf(a[8], a[9]); u0.y = pkbf(a[10], a[11]);
            u1.x = pkbf(a[12], a[13]); u1.y = pkbf(a[14], a[15]);
            *(uint2*)(&mt[q * 256 + ((c0 + 8) ^ ((q & 7) * 8))]) = u0;
            *(uint2*)(&mt[q * 256 + ((c0 + 12) ^ ((q & 7) * 8))]) = u1;
        }
    }
    __syncthreads();
    {
        int w = tid >> 6, lane = tid & 63;
        int fr = lane & 15, kg = lane >> 4;
        f32x4 acc[2][4] = {};
        for (int k0 = 0; k0 < 256; k0 += 32) {
            bf16x8 a0 = *(const bf16x8*)(WoT + (long)(w * 32 + fr) * 256 + k0 + kg * 8);
            bf16x8 a1 = *(const bf16x8*)(WoT + (long)(w * 32 + 16 + fr) * 256 + k0 + kg * 8);
#pragma unroll
            for (int qt = 0; qt < 4; ++qt) {
                int row = qt * 16 + fr;
                bf16x8 b = *(const bf16x8*)(&mt[row * 256 + ((k0 + kg * 8) ^ ((row & 7) * 8))]);
                acc[0][qt] = __builtin_amdgcn_mfma_f32_16x16x32_bf16(a0, b, acc[0][qt], 0, 0, 0);
                acc[1][qt] = __builtin_amdgcn_mfma_f32_16x16x32_bf16(a1, b, acc[1][qt], 0, 0, 0);
            }
        }
#pragma unroll
        for (int dt = 0; dt < 2; ++dt)
#pragma unroll
            for (int qt = 0; qt < 4; ++qt)
#pragma unroll
                for (int r = 0; r < 4; ++r)
                    PT[(long)(w * 32 + dt * 16 + kg * 4 + r) * N_TOK + q0 + qt * 16 + fr] =
                        f2bf(acc[dt][qt][r]);
    }
}

// ---------------- fused: part[c] = (sum_f w_f*rpe[f] + b)[.,Kc] @ PT^T ------
// PT = (mho @ Wo)^T bf16 [128][4096]. N=128. T14: A-loads early, LDS-write late.
__global__ __launch_bounds__(512) void gemm_big_fused(
    const float* __restrict__ rpe, const float* __restrict__ rpe_w,
    const float* __restrict__ rpe_b, const ushort* __restrict__ PT,
    float* __restrict__ part) {
    int mt = blockIdx.x, cz = blockIdx.y;
    int tid = threadIdx.x;
    int w = tid >> 6, lane = tid & 63;
    int fr = lane & 15, kg = lane >> 4;
    int lr = lane >> 3, lc = lane & 7;
    int swz = (lc ^ (lr & 7)) * 8;
    int ms = w >> 1, nh = w & 1;
    __shared__ ushort Bt[2][128 * 64];
    __shared__ ushort At[2][64 * 64];
    int m0 = mt * 64;
    long kbase = (long)cz * (N_TOK / NC_GEMM);
    float w0 = rpe_w[0], w1 = rpe_w[1], w2 = rpe_w[2], w3 = rpe_w[3], w4 = rpe_w[4];
    float bb = rpe_b[0];
    auto stage_B = [&](int buf, int s) {
        const ushort* src = PT + kbase + s * 64 + swz;
#pragma unroll
        for (int j = 0; j < 2; ++j) {
            int i = w * 2 + j;
            int row = i * 8 + lr;
            __builtin_amdgcn_global_load_lds(
                (const __attribute__((address_space(1))) unsigned int*)(src + (long)row * N_TOK),
                (__attribute__((address_space(3))) unsigned int*)(&Bt[buf][i * 512]), 16, 0, 0);
        }
    };
    float4 pA[10];  // 2 rounds x 5 planes, statically indexed
    auto load_A = [&](int s) {
        const float* base = rpe + (long)m0 * N_TOK + kbase + s * 64;
#pragma unroll
        for (int rnd = 0; rnd < 2; ++rnd) {
            int idx = tid + rnd * 512;
            int row = idx >> 4, c4 = (idx & 15) * 4;
            const float* pr = base + (long)row * N_TOK + c4;
#pragma unroll
            for (int pl = 0; pl < 5; ++pl)
                pA[rnd * 5 + pl] = *(const float4*)(pr + (long)pl * ((long)N_TOK * N_TOK));
        }
    };
    auto write_A = [&](int buf) {
#pragma unroll
        for (int rnd = 0; rnd < 2; ++rnd) {
            int idx = tid + rnd * 512;
            int row = idx >> 4, c4 = (idx & 15) * 4;
            float4 p0 = pA[rnd * 5], p1 = pA[rnd * 5 + 1], p2 = pA[rnd * 5 + 2];
            float4 p3 = pA[rnd * 5 + 3], p4 = pA[rnd * 5 + 4];
            float v0 = bb + w0 * p0.x + w1 * p1.x + w2 * p2.x + w3 * p3.x + w4 * p4.x;
            float v1 = bb + w0 * p0.y + w1 * p1.y + w2 * p2.y + w3 * p3.y + w4 * p4.y;
            float v2 = bb + w0 * p0.z + w1 * p1.z + w2 * p2.z + w3 * p3.z + w4 * p4.z;
            float v3 = bb + w0 * p0.w + w1 * p1.w + w2 * p2.w + w3 * p3.w + w4 * p4.w;
            uint2 u;
            u.x = pkbf(v0, v1);
            u.y = pkbf(v2, v3);
            *(uint2*)(&At[buf][row * 64 + (c4 ^ ((row & 7) * 8))]) = u;
        }
    };
    f32x4 acc[4] = {};
    load_A(0);
    stage_B(0, 0);
    write_A(0);
    __syncthreads();
    const int NS = (N_TOK / NC_GEMM) / 64;
    int arow = ms * 16 + fr;
    for (int s = 0; s < NS; ++s) {
        int buf = s & 1;
        if (s + 1 < NS) { stage_B(buf ^ 1, s + 1); load_A(s + 1); }
#pragma unroll
        for (int ks = 0; ks < 2; ++ks) {
            bf16x8 av = *(const bf16x8*)(&At[buf][arow * 64 + ((ks * 32 + kg * 8) ^ ((arow & 7) * 8))]);
#pragma unroll
            for (int nf = 0; nf < 4; ++nf) {
                int row = nh * 64 + nf * 16 + fr;
                bf16x8 b = *(const bf16x8*)(&Bt[buf][row * 64 + ((ks * 32 + kg * 8) ^ ((row & 7) * 8))]);
                acc[nf] = __builtin_amdgcn_mfma_f32_16x16x32_bf16(av, b, acc[nf], 0, 0, 0);
            }
        }
        if (s + 1 < NS) write_A(buf ^ 1);  // vmcnt wait lands AFTER the MFMAs
        __syncthreads();
    }
    float* pb = part + ((long)cz * N_TOK + m0 + ms * 16 + kg * 4) * 128 + nh * 64 + fr;
#pragma unroll
    for (int nf = 0; nf < 4; ++nf)
#pragma unroll
        for (int r = 0; r < 4; ++r)
            pb[(long)r * 128 + nf * 16] = acc[nf][r];
}

// ---------------- megatail: sum parts + bo + x -> LN1 -> FFN -> LN2 -> out --
__global__ __launch_bounds__(256) void megatail(
    const float* __restrict__ gpart, const float* __restrict__ bo,
    const float* __restrict__ x, const float* __restrict__ g1,
    const float* __restrict__ lb1, const ushort* __restrict__ W1T,
    const float* __restrict__ b1, const ushort* __restrict__ W2T,
    const float* __restrict__ b2, const float* __restrict__ g2,
    const float* __restrict__ lb2, float* __restrict__ out) {
    int r0 = blockIdx.x * 16;
    int tid = threadIdx.x;
    int w = tid >> 6, lane = tid & 63;
    int fr = lane & 15, kg = lane >> 4;
    __shared__ float x1f[16][132];
    __shared__ ushort x1b[16][128];
    __shared__ ushort hbuf[16][256];
    __shared__ float otile[16][132];
    int row = tid >> 4, c0 = (tid & 15) * 8;
    // phase 0: v = sum_c gpart[c] + bo + x, then LN1 (all in-register per row)
    {
        float v[8];
        float4 s0 = {0.f, 0.f, 0.f, 0.f}, s1 = {0.f, 0.f, 0.f, 0.f};
#pragma unroll
        for (int c = 0; c < NC_GEMM; ++c) {
            const float* pr = gpart + ((long)c * N_TOK + r0 + row) * 128 + c0;
            float4 a = *(const float4*)(pr);
            float4 b = *(const float4*)(pr + 4);
            s0.x += a.x; s0.y += a.y; s0.z += a.z; s0.w += a.w;
            s1.x += b.x; s1.y += b.y; s1.z += b.z; s1.w += b.w;
        }
        const float* xr = x + (long)(r0 + row) * 128 + c0;
        v[0] = s0.x + bo[c0 + 0] + xr[0];
        v[1] = s0.y + bo[c0 + 1] + xr[1];
        v[2] = s0.z + bo[c0 + 2] + xr[2];
        v[3] = s0.w + bo[c0 + 3] + xr[3];
        v[4] = s1.x + bo[c0 + 4] + xr[4];
        v[5] = s1.y + bo[c0 + 5] + xr[5];
        v[6] = s1.z + bo[c0 + 6] + xr[6];
        v[7] = s1.w + bo[c0 + 7] + xr[7];
        float s = 0.f;
#pragma unroll
        for (int jj = 0; jj < 8; ++jj) s += v[jj];
#pragma unroll
        for (int off = 1; off < 16; off <<= 1) s += __shfl_xor(s, off);
        float mean = s * (1.0f / 128.0f);
        float ss = 0.f;
#pragma unroll
        for (int jj = 0; jj < 8; ++jj) { float d = v[jj] - mean; ss += d * d; }
#pragma unroll
        for (int off = 1; off < 16; off <<= 1) ss += __shfl_xor(ss, off);
        float rstd = rsqrtf(ss * (1.0f / 128.0f) + 1e-5f);
        union { bf16x8 vec; ushort us[8]; } pk8;
#pragma unroll
        for (int jj = 0; jj < 8; ++jj) {
            float y = (v[jj] - mean) * rstd * g1[c0 + jj] + lb1[c0 + jj];
            x1f[row][c0 + jj] = y;
            pk8.us[jj] = f2bf(y);
        }
        *(bf16x8*)(&x1b[row][c0 ^ ((row & 7) * 8)]) = pk8.vec;
    }
    __syncthreads();
    // phase 1: h = relu(x1b @ W1T^T + b1)  (wave w -> cols w*64..w*64+63)
    {
        f32x4 a1[4] = {};
#pragma unroll
        for (int ks = 0; ks < 4; ++ks) {
            bf16x8 a = *(const bf16x8*)(&x1b[fr][(ks * 32 + kg * 8) ^ ((fr & 7) * 8)]);
#pragma unroll
            for (int t = 0; t < 4; ++t) {
                bf16x8 b = *(const bf16x8*)(W1T + (long)(w * 64 + t * 16 + fr) * 128 + ks * 32 + kg * 8);
                a1[t] = __builtin_amdgcn_mfma_f32_16x16x32_bf16(a, b, a1[t], 0, 0, 0);
            }
        }
#pragma unroll
        for (int t = 0; t < 4; ++t) {
            int col = w * 64 + t * 16 + fr;
            float bs = b1[col];
#pragma unroll
            for (int r = 0; r < 4; ++r) {
                int rr = kg * 4 + r;
                hbuf[rr][col ^ ((rr & 7) * 8)] = f2bf(fmaxf(a1[t][r] + bs, 0.f));
            }
        }
    }
    __syncthreads();
    // phase 2: o = h @ W2T^T + b2 + x1  (wave w -> cols w*32..w*32+31)
    {
        f32x4 a2[2] = {};
#pragma unroll
        for (int ks = 0; ks < 8; ++ks) {
            bf16x8 a = *(const bf16x8*)(&hbuf[fr][(ks * 32 + kg * 8) ^ ((fr & 7) * 8)]);
#pragma unroll
            for (int t = 0; t < 2; ++t) {
                bf16x8 b = *(const bf16x8*)(W2T + (long)(w * 32 + t * 16 + fr) * 256 + ks * 32 + kg * 8);
                a2[t] = __builtin_amdgcn_mfma_f32_16x16x32_bf16(a, b, a2[t], 0, 0, 0);
            }
        }
#pragma unroll
        for (int t = 0; t < 2; ++t) {
            int col = w * 32 + t * 16 + fr;
            float bs = b2[col];
#pragma unroll
            for (int r = 0; r < 4; ++r) {
                int rr = kg * 4 + r;
                otile[rr][col] = a2[t][r] + bs + x1f[rr][col];
            }
        }
    }
    __syncthreads();
    // phase 2b: LN2 -> out fp32
    {
        float v[8];
        float s = 0.f;
#pragma unroll
        for (int jj = 0; jj < 8; ++jj) { v[jj] = otile[row][c0 + jj]; s += v[jj]; }
#pragma unroll
        for (int off = 1; off < 16; off <<= 1) s += __shfl_xor(s, off);
        float mean = s * (1.0f / 128.0f);
        float ss = 0.f;
#pragma unroll
        for (int jj = 0; jj < 8; ++jj) { float d = v[jj] - mean; ss += d * d; }
#pragma unroll
        for (int off = 1; off < 16; off <<= 1) ss += __shfl_xor(ss, off);
        float rstd = rsqrtf(ss * (1.0f / 128.0f) + 1e-5f);
#pragma unroll
        for (int jj = 0; jj < 8; ++jj) {
            float y = (v[jj] - mean) * rstd * g2[c0 + jj] + lb2[c0 + jj];
            out[(long)(r0 + row) * 128 + c0 + jj] = y;
        }
    }
}

extern "C" void kernel_launch(void* const* d_in, const int* in_sizes, int n_in,
                              void* d_out, int out_size, void* d_ws, size_t ws_size,
                              hipStream_t stream) {
    const float* x     = (const float*)d_in[0];
    const float* rpe   = (const float*)d_in[1];
    const float* Wq    = (const float*)d_in[2];
    const float* bq    = (const float*)d_in[3];
    const float* Wk    = (const float*)d_in[4];
    const float* bk    = (const float*)d_in[5];
    const float* Wv    = (const float*)d_in[6];
    const float* bv    = (const float*)d_in[7];
    const float* rpe_w = (const float*)d_in[8];
    const float* rpe_b = (const float*)d_in[9];
    const float* Wo    = (const float*)d_in[10];
    const float* bo    = (const float*)d_in[11];
    const float* W1    = (const float*)d_in[12];
    const float* b1    = (const float*)d_in[13];
    const float* W2    = (const float*)d_in[14];
    const float* b2    = (const float*)d_in[15];
    const float* g1    = (const float*)d_in[16];
    const float* lb1   = (const float*)d_in[17];
    const float* g2    = (const float*)d_in[18];
    const float* lb2   = (const float*)d_in[19];

    char* wp = (char*)d_ws;
    auto alloc = [&](size_t sz) { char* p = wp; wp += (sz + 255) & ~(size_t)255; return p; };
    ushort* xb    = (ushort*)alloc((size_t)4096 * 128 * 2);
    ushort* WqT   = (ushort*)alloc((size_t)4 * 64 * 128 * 2);
    ushort* WkT   = (ushort*)alloc((size_t)4 * 64 * 128 * 2);
    ushort* WvT   = (ushort*)alloc((size_t)4 * 64 * 128 * 2);
    ushort* WoT   = (ushort*)alloc((size_t)128 * 256 * 2);
    ushort* W1T   = (ushort*)alloc((size_t)256 * 128 * 2);
    ushort* W2T   = (ushort*)alloc((size_t)128 * 256 * 2);
    ushort* qb    = (ushort*)alloc((size_t)4 * 4096 * 64 * 2);
    ushort* kbuf  = (ushort*)alloc((size_t)4 * 4096 * 64 * 2);
    ushort* vT    = (ushort*)alloc((size_t)4 * 64 * 4096 * 2);
    ushort* PTb   = (ushort*)alloc((size_t)128 * 4096 * 2);
    ushort* opart = (ushort*)alloc((size_t)NC_ATT * 4 * 4096 * 64 * 2);
    float*  mlprt = (float*)alloc((size_t)NC_ATT * 4 * 4096 * 2 * 4);
    float*  gpart = (float*)alloc((size_t)NC_GEMM * 4096 * 128 * 4);

    prep_all<<<1280, 256, 0, stream>>>(x, Wq, Wk, Wv, Wo, W1, W2,
                                       xb, WqT, WkT, WvT, WoT, W1T, W2T);
    qkv_proj<<<dim3(64, 12), 256, 0, stream>>>(xb, WqT, WkT, WvT, bq, bk, bv, qb, kbuf, vT);
    attn_flash2<<<dim3(64, 4, NC_ATT), 256, 0, stream>>>(qb, kbuf, vT, opart, mlprt);
    combine_wo<<<64, 256, 0, stream>>>(opart, mlprt, WoT, PTb);
    gemm_big_fused<<<dim3(64, NC_GEMM), 512, 0, stream>>>(rpe, rpe_w, rpe_b, PTb, gpart);
    megatail<<<256, 256, 0, stream>>>(gpart, bo, x, g1, lb1, W1T, b1, W2T, b2,
                                      g2, lb2, (float*)d_out);
}

// Round 7
// 148.797 us; speedup vs baseline: 2.6114x; 1.0186x over previous
//
#include <hip/hip_runtime.h>

typedef __attribute__((ext_vector_type(8))) short bf16x8;
typedef __attribute__((ext_vector_type(4))) float f32x4;

#define N_TOK 4096
#define NC_ATT 4
#define NC_GEMM 8

static __device__ __forceinline__ ushort f2bf(float f) {
    union { float f; unsigned u; } x; x.f = f;
    unsigned u = x.u;
    unsigned r = (u + 0x7FFFu + ((u >> 16) & 1u)) >> 16;
    return (ushort)r;
}
static __device__ __forceinline__ unsigned pkbf(float a, float b) {
    return (unsigned)f2bf(a) | ((unsigned)f2bf(b) << 16);
}
static __device__ __forceinline__ float bf2f(ushort u) {
    union { unsigned u; float f; } x; x.u = (unsigned)u << 16; return x.f;
}

// ---------------- prep: cast x + all weight transposes in one kernel ------
__global__ void prep_all(const float* __restrict__ x,
                         const float* __restrict__ Wq, const float* __restrict__ Wk,
                         const float* __restrict__ Wv, const float* __restrict__ Wo,
                         const float* __restrict__ W1, const float* __restrict__ W2,
                         ushort* __restrict__ xb, ushort* __restrict__ WqT,
                         ushort* __restrict__ WkT, ushort* __restrict__ WvT,
                         ushort* __restrict__ WoT, ushort* __restrict__ W1T,
                         ushort* __restrict__ W2T) {
    int i = blockIdx.x * 256 + threadIdx.x;
    if (i < 131072) {  // x: 4096*128/4 quads
        float4 v = ((const float4*)x)[i];
        ushort4 o;
        o.x = f2bf(v.x); o.y = f2bf(v.y); o.z = f2bf(v.z); o.w = f2bf(v.w);
        ((ushort4*)xb)[i] = o;
        return;
    }
    int j = i - 131072;
    int t = j >> 15, e = j & 32767;
    if (t < 3) {  // Wq/Wk/Wv [4][128][64] -> [4][64][128]
        const float* src = (t == 0 ? Wq : t == 1 ? Wk : Wv);
        ushort* dst = (t == 0 ? WqT : t == 1 ? WkT : WvT);
        int h = e >> 13, rem = e & 8191, d = rem >> 6, k = rem & 63;
        dst[h * 8192 + k * 128 + d] = f2bf(src[e]);
    } else if (t == 3) {  // Wo [256][128] -> [128][256]
        int r = e >> 7, c = e & 127;
        WoT[c * 256 + r] = f2bf(Wo[e]);
    } else if (t == 4) {  // W1 [128][256] -> [256][128]
        int r = e >> 8, c = e & 255;
        W1T[c * 128 + r] = f2bf(W1[e]);
    } else {  // W2 [256][128] -> [128][256]
        int r = e >> 7, c = e & 127;
        W2T[c * 256 + r] = f2bf(W2[e]);
    }
}

// ---------------- QKV projection: relu(xb @ W^T + b) ------------------------
// q pre-scaled by 0.125*log2(e) so attention works in exp2 domain.
__global__ __launch_bounds__(256) void qkv_proj(
    const ushort* __restrict__ xb, const ushort* __restrict__ WqT,
    const ushort* __restrict__ WkT, const ushort* __restrict__ WvT,
    const float* __restrict__ bq, const float* __restrict__ bk, const float* __restrict__ bv,
    ushort* __restrict__ qb, ushort* __restrict__ kb, ushort* __restrict__ vT) {
    int m0 = blockIdx.x * 64;
    int h = blockIdx.y & 3, which = blockIdx.y >> 2;
    int wave = threadIdx.x >> 6, lane = threadIdx.x & 63;
    int fr = lane & 15, kg = lane >> 4;
    int wm = m0 + wave * 16;
    const ushort* WT = (which == 0 ? WqT : which == 1 ? WkT : WvT) + (long)h * 64 * 128;
    const float* bias = (which == 0 ? bq : which == 1 ? bk : bv) + h * 64;
    f32x4 acc[4] = {};
    for (int k0 = 0; k0 < 128; k0 += 32) {
        bf16x8 a = *(const bf16x8*)(xb + (long)(wm + fr) * 128 + k0 + kg * 8);
#pragma unroll
        for (int t = 0; t < 4; ++t) {
            bf16x8 b = *(const bf16x8*)(WT + (long)(t * 16 + fr) * 128 + k0 + kg * 8);
            acc[t] = __builtin_amdgcn_mfma_f32_16x16x32_bf16(a, b, acc[t], 0, 0, 0);
        }
    }
    int rb = wm + kg * 4;
#pragma unroll
    for (int t = 0; t < 4; ++t) {
        int col = t * 16 + fr;
        float bs = bias[col];
        if (which == 2) {
            ushort4 o;
            o.x = f2bf(fmaxf(acc[t][0] + bs, 0.f));
            o.y = f2bf(fmaxf(acc[t][1] + bs, 0.f));
            o.z = f2bf(fmaxf(acc[t][2] + bs, 0.f));
            o.w = f2bf(fmaxf(acc[t][3] + bs, 0.f));
            *(ushort4*)(vT + ((long)h * 64 + col) * N_TOK + rb) = o;
        } else {
            ushort* dst = (which == 0 ? qb : kb) + (long)h * N_TOK * 64;
            float scl = (which == 0) ? 0.125f * 1.44269504f : 1.0f;
#pragma unroll
            for (int r = 0; r < 4; ++r)
                dst[(long)(rb + r) * 64 + col] = f2bf(fmaxf(acc[t][r] + bs, 0.f) * scl);
        }
    }
}

// ---------------- flash attention: swapped QK^T, exp2 domain, defer-max -----
__global__ __launch_bounds__(256) void attn_flash2(
    const ushort* __restrict__ qb, const ushort* __restrict__ kb,
    const ushort* __restrict__ vT, ushort* __restrict__ opart,
    float* __restrict__ mlpart) {
    int qt = blockIdx.x, h = blockIdx.y, cz = blockIdx.z;
    int w = threadIdx.x >> 6, lane = threadIdx.x & 63;
    int fr = lane & 15, kg = lane >> 4;
    int lr = lane >> 3, lc = lane & 7;
    int swz = (lc ^ (lr & 7)) * 8;
    __shared__ ushort Kt[2][64 * 64];
    __shared__ ushort Vt[2][64 * 64];
    __shared__ ushort Pl[4][16 * 64];
    const ushort* qh = qb + (long)h * N_TOK * 64;
    const ushort* kh = kb + (long)h * N_TOK * 64;
    const ushort* vh = vT + (long)h * 64 * N_TOK;
    int q0 = qt * 64 + w * 16;
    bf16x8 qf0 = *(const bf16x8*)(qh + (long)(q0 + fr) * 64 + kg * 8);
    bf16x8 qf1 = *(const bf16x8*)(qh + (long)(q0 + fr) * 64 + 32 + kg * 8);
    f32x4 o[4] = {};
    float mrun = -1e30f, lrun = 0.f;  // per-lane stats for q = q0 + fr (log2 dom)
    int nbase = cz * (N_TOK / NC_ATT);
    auto stage = [&](int buf, int s) {
        int n0 = nbase + s * 64;
#pragma unroll
        for (int j = 0; j < 2; ++j) {
            int i = w * 2 + j;
            int row = i * 8 + lr;
            __builtin_amdgcn_global_load_lds(
                (const __attribute__((address_space(1))) unsigned int*)(kh + (long)(n0 + row) * 64 + swz),
                (__attribute__((address_space(3))) unsigned int*)(&Kt[buf][i * 512]), 16, 0, 0);
        }
#pragma unroll
        for (int j = 0; j < 2; ++j) {
            int i = w * 2 + j;
            int row = i * 8 + lr;
            __builtin_amdgcn_global_load_lds(
                (const __attribute__((address_space(1))) unsigned int*)(vh + (long)row * N_TOK + n0 + swz),
                (__attribute__((address_space(3))) unsigned int*)(&Vt[buf][i * 512]), 16, 0, 0);
        }
    };
    stage(0, 0);
    __syncthreads();
    const int NS = (N_TOK / NC_ATT) / 64;
    for (int s = 0; s < NS; ++s) {
        int buf = s & 1;
        if (s + 1 < NS) stage(buf ^ 1, s + 1);
        // S^T = K @ Q^T: lane holds kv = t*16+kg*4+r for q = q0+fr
        f32x4 sc[4] = {};
#pragma unroll
        for (int t = 0; t < 4; ++t) {
            int row = t * 16 + fr;
            bf16x8 k0 = *(const bf16x8*)(&Kt[buf][row * 64 + ((kg * 8) ^ ((row & 7) * 8))]);
            bf16x8 k1 = *(const bf16x8*)(&Kt[buf][row * 64 + ((32 + kg * 8) ^ ((row & 7) * 8))]);
            sc[t] = __builtin_amdgcn_mfma_f32_16x16x32_bf16(k0, qf0, sc[t], 0, 0, 0);
            sc[t] = __builtin_amdgcn_mfma_f32_16x16x32_bf16(k1, qf1, sc[t], 0, 0, 0);
        }
        float mx = sc[0][0];
#pragma unroll
        for (int t = 0; t < 4; ++t)
#pragma unroll
            for (int r = 0; r < 4; ++r) mx = fmaxf(mx, sc[t][r]);
        mx = fmaxf(mx, __shfl_xor(mx, 16));
        mx = fmaxf(mx, __shfl_xor(mx, 32));
        // defer-max: only rescale when tile max grew past threshold (log2 units)
        if (__any(mx - mrun > 8.f)) {
            float mnew = fmaxf(mrun, mx);
            float alpha = exp2f(mrun - mnew);
            lrun *= alpha;
            mrun = mnew;
            float aq[4];
#pragma unroll
            for (int r = 0; r < 4; ++r) aq[r] = __shfl(alpha, kg * 4 + r);
#pragma unroll
            for (int t = 0; t < 4; ++t)
#pragma unroll
                for (int r = 0; r < 4; ++r) o[t][r] *= aq[r];
        }
        float rs = 0.f;
#pragma unroll
        for (int t = 0; t < 4; ++t)
#pragma unroll
            for (int r = 0; r < 4; ++r) {
                float p = exp2f(sc[t][r] - mrun);
                sc[t][r] = p;
                rs += p;
            }
        rs += __shfl_xor(rs, 16);
        rs += __shfl_xor(rs, 32);
        lrun += rs;
        // P[q=fr][kv]: pack 4 consecutive kv per tile -> b64 write
#pragma unroll
        for (int t = 0; t < 4; ++t) {
            uint2 u;
            u.x = pkbf(sc[t][0], sc[t][1]);
            u.y = pkbf(sc[t][2], sc[t][3]);
            *(uint2*)(&Pl[w][fr * 64 + ((t * 16 + kg * 4) ^ ((fr & 7) * 8))]) = u;
        }
#pragma unroll
        for (int ks = 0; ks < 2; ++ks) {
            bf16x8 pf = *(const bf16x8*)(&Pl[w][fr * 64 + ((ks * 32 + kg * 8) ^ ((fr & 7) * 8))]);
#pragma unroll
            for (int t = 0; t < 4; ++t) {
                int row = t * 16 + fr;
                bf16x8 b = *(const bf16x8*)(&Vt[buf][row * 64 + ((ks * 32 + kg * 8) ^ ((row & 7) * 8))]);
                o[t] = __builtin_amdgcn_mfma_f32_16x16x32_bf16(pf, b, o[t], 0, 0, 0);
            }
        }
        __syncthreads();
    }
    float linv = 1.0f / lrun;
    float lq[4];
#pragma unroll
    for (int r = 0; r < 4; ++r) lq[r] = __shfl(linv, kg * 4 + r);
    ushort* ob = opart + (((long)cz * 4 + h) * N_TOK + q0 + kg * 4) * 64;
#pragma unroll
    for (int t = 0; t < 4; ++t)
#pragma unroll
        for (int r = 0; r < 4; ++r)
            ob[(long)r * 64 + t * 16 + fr] = f2bf(o[t][r] * lq[r]);
    if (lane < 16) {
        float* mlb = mlpart + (((long)cz * 4 + h) * N_TOK + q0 + lane) * 2;
        mlb[0] = mrun;
        mlb[1] = lrun;
    }
}

// ---------------- combine KV-chunks + Wo-projection -> PT bf16 [128][4096] --
// 256 blocks x 16 q. Phase A: mho tile [16 q][256 c] in LDS (XOR swizzle).
// Phase B: PT[:, qtile] = WoT @ mho_tile^T via MFMA.
__global__ __launch_bounds__(256) void combine_wo(
    const ushort* __restrict__ opart, const float* __restrict__ mlpart,
    const ushort* __restrict__ WoT, ushort* __restrict__ PT) {
    int q0 = blockIdx.x * 16;
    int tid = threadIdx.x;
    __shared__ ushort mt[16 * 256];
    {
        int q = tid >> 4, cg = tid & 15;  // 16 rows x 16 col-groups (16 cols each)
        int h = cg >> 2;                  // head for this 16-col group
        long qg = q0 + q;
        float m[NC_ATT], l[NC_ATT], M = -1e30f;
#pragma unroll
        for (int c = 0; c < NC_ATT; ++c) {
            const float* mlb = mlpart + (((long)c * 4 + h) * N_TOK + qg) * 2;
            m[c] = mlb[0]; l[c] = mlb[1];
            M = fmaxf(M, m[c]);
        }
        float L = 0.f, co[NC_ATT];
#pragma unroll
        for (int c = 0; c < NC_ATT; ++c) { co[c] = exp2f(m[c] - M) * l[c]; L += co[c]; }
        float inv = 1.0f / L;
#pragma unroll
        for (int c = 0; c < NC_ATT; ++c) co[c] *= inv;
        float a[16];
#pragma unroll
        for (int j = 0; j < 16; ++j) a[j] = 0.f;
#pragma unroll
        for (int c = 0; c < NC_ATT; ++c) {
            const ushort* pr = opart + (((long)c * 4 + h) * N_TOK + qg) * 64 + (cg & 3) * 16;
            bf16x8 v0 = *(const bf16x8*)(pr);
            bf16x8 v1 = *(const bf16x8*)(pr + 8);
#pragma unroll
            for (int j = 0; j < 8; ++j) {
                a[j] += co[c] * bf2f((ushort)v0[j]);
                a[8 + j] += co[c] * bf2f((ushort)v1[j]);
            }
        }
        int c0 = cg * 16;
#pragma unroll
        for (int g = 0; g < 4; ++g) {
            uint2 u;
            u.x = pkbf(a[g * 4 + 0], a[g * 4 + 1]);
            u.y = pkbf(a[g * 4 + 2], a[g * 4 + 3]);
            *(uint2*)(&mt[q * 256 + ((c0 + g * 4) ^ ((q & 7) * 8))]) = u;
        }
    }
    __syncthreads();
    {
        int w = tid >> 6, lane = tid & 63;
        int fr = lane & 15, kg = lane >> 4;
        f32x4 acc[2] = {};
        for (int k0 = 0; k0 < 256; k0 += 32) {
            bf16x8 a0 = *(const bf16x8*)(WoT + (long)(w * 32 + fr) * 256 + k0 + kg * 8);
            bf16x8 a1 = *(const bf16x8*)(WoT + (long)(w * 32 + 16 + fr) * 256 + k0 + kg * 8);
            bf16x8 b = *(const bf16x8*)(&mt[fr * 256 + ((k0 + kg * 8) ^ ((fr & 7) * 8))]);
            acc[0] = __builtin_amdgcn_mfma_f32_16x16x32_bf16(a0, b, acc[0], 0, 0, 0);
            acc[1] = __builtin_amdgcn_mfma_f32_16x16x32_bf16(a1, b, acc[1], 0, 0, 0);
        }
#pragma unroll
        for (int dt = 0; dt < 2; ++dt)
#pragma unroll
            for (int r = 0; r < 4; ++r)
                PT[(long)(w * 32 + dt * 16 + kg * 4 + r) * N_TOK + q0 + fr] =
                    f2bf(acc[dt][r]);
    }
}

// ---------------- fused: part[c] = (sum_f w_f*rpe[f] + b)[.,Kc] @ PT^T ------
// Contiguous-read restructure: per 256-K phase, stream A (1KB row-runs,
// lane-consecutive float4s) -> pack -> 32KB swizzled LDS tile; then 4 MFMA
// sub-steps vs double-buffered B. LDS 64KB -> 2 blocks/CU.
__global__ __launch_bounds__(512) void gemm_big_fused(
    const float* __restrict__ rpe, const float* __restrict__ rpe_w,
    const float* __restrict__ rpe_b, const ushort* __restrict__ PT,
    float* __restrict__ part) {
    int mt = blockIdx.x, cz = blockIdx.y;
    int tid = threadIdx.x;
    int w = tid >> 6, lane = tid & 63;
    int fr = lane & 15, kg = lane >> 4;
    int lr = lane >> 3, lc = lane & 7;
    int swzB = (lc ^ (lr & 7)) * 8;
    int ms = w >> 1, nh = w & 1;
    __shared__ ushort At[64 * 256];     // 32 KB
    __shared__ ushort Bt[2][128 * 64];  // 32 KB
    int m0 = mt * 64;
    long kbase = (long)cz * (N_TOK / NC_GEMM);
    float w0 = rpe_w[0], w1 = rpe_w[1], w2 = rpe_w[2], w3 = rpe_w[3], w4 = rpe_w[4];
    float bb = rpe_b[0];
    const long PLANE = (long)N_TOK * N_TOK;
    int arow = ms * 16 + fr;             // MFMA A-row
    int lrow = tid >> 3, seg = tid & 7;  // loader: row, float4-lane within 8
    auto stage_B = [&](int buf, int sb) {
        const ushort* src = PT + kbase + sb * 64 + swzB;
#pragma unroll
        for (int j = 0; j < 2; ++j) {
            int i = w * 2 + j;
            int row = i * 8 + lr;
            __builtin_amdgcn_global_load_lds(
                (const __attribute__((address_space(1))) unsigned int*)(src + (long)row * N_TOK),
                (__attribute__((address_space(3))) unsigned int*)(&Bt[buf][i * 512]), 16, 0, 0);
        }
    };
    f32x4 acc[4] = {};
    for (int p = 0; p < 2; ++p) {
        if (p == 0) stage_B(0, 0);
        // ---- A stream: 8 groups; group g covers cols (seg + g*8)*4 .. +3 ----
        const float* base = rpe + (long)(m0 + lrow) * N_TOK + kbase + p * 256;
#pragma unroll
        for (int rnd = 0; rnd < 4; ++rnd) {
            float4 pv[2][5];
#pragma unroll
            for (int g = 0; g < 2; ++g) {
                int col = (seg + (rnd * 2 + g) * 8) * 4;
#pragma unroll
                for (int pl = 0; pl < 5; ++pl)
                    pv[g][pl] = *(const float4*)(base + col + pl * PLANE);
            }
#pragma unroll
            for (int g = 0; g < 2; ++g) {
                int col = (seg + (rnd * 2 + g) * 8) * 4;
                float4 a0 = pv[g][0], a1 = pv[g][1], a2 = pv[g][2], a3 = pv[g][3], a4 = pv[g][4];
                uint2 u;
                u.x = pkbf(bb + w0 * a0.x + w1 * a1.x + w2 * a2.x + w3 * a3.x + w4 * a4.x,
                           bb + w0 * a0.y + w1 * a1.y + w2 * a2.y + w3 * a3.y + w4 * a4.y);
                u.y = pkbf(bb + w0 * a0.z + w1 * a1.z + w2 * a2.z + w3 * a3.z + w4 * a4.z,
                           bb + w0 * a0.w + w1 * a1.w + w2 * a2.w + w3 * a3.w + w4 * a4.w);
                *(uint2*)(&At[lrow * 256 + (col ^ ((lrow & 7) * 8))]) = u;
            }
        }
        __syncthreads();  // At ready; Bt[sub-step p*4] ready (pre-barrier drain)
        // ---- MFMA sub-steps over the 256-col A tile ----
        for (int ks = 0; ks < 4; ++ks) {
            int sb = p * 4 + ks;
            if (sb + 1 < 8) stage_B((sb + 1) & 1, sb + 1);
#pragma unroll
            for (int k2 = 0; k2 < 2; ++k2) {
                int c = ks * 64 + k2 * 32 + kg * 8;
                bf16x8 av = *(const bf16x8*)(&At[arow * 256 + (c ^ ((arow & 7) * 8))]);
#pragma unroll
                for (int nf = 0; nf < 4; ++nf) {
                    int row = nh * 64 + nf * 16 + fr;
                    bf16x8 b = *(const bf16x8*)(&Bt[sb & 1][row * 64 + ((k2 * 32 + kg * 8) ^ ((row & 7) * 8))]);
                    acc[nf] = __builtin_amdgcn_mfma_f32_16x16x32_bf16(av, b, acc[nf], 0, 0, 0);
                }
            }
            __syncthreads();
        }
    }
    float* pb = part + ((long)cz * N_TOK + m0 + ms * 16 + kg * 4) * 128 + nh * 64 + fr;
#pragma unroll
    for (int nf = 0; nf < 4; ++nf)
#pragma unroll
        for (int r = 0; r < 4; ++r)
            pb[(long)r * 128 + nf * 16] = acc[nf][r];
}

// ---------------- megatail: sum parts + bo + x -> LN1 -> FFN -> LN2 -> out --
__global__ __launch_bounds__(256) void megatail(
    const float* __restrict__ gpart, const float* __restrict__ bo,
    const float* __restrict__ x, const float* __restrict__ g1,
    const float* __restrict__ lb1, const ushort* __restrict__ W1T,
    const float* __restrict__ b1, const ushort* __restrict__ W2T,
    const float* __restrict__ b2, const float* __restrict__ g2,
    const float* __restrict__ lb2, float* __restrict__ out) {
    int r0 = blockIdx.x * 16;
    int tid = threadIdx.x;
    int w = tid >> 6, lane = tid & 63;
    int fr = lane & 15, kg = lane >> 4;
    __shared__ float x1f[16][132];
    __shared__ ushort x1b[16][128];
    __shared__ ushort hbuf[16][256];
    __shared__ float otile[16][132];
    int row = tid >> 4, c0 = (tid & 15) * 8;
    // phase 0: v = sum_c gpart[c] + bo + x, then LN1 (all in-register per row)
    {
        float v[8];
        float4 s0 = {0.f, 0.f, 0.f, 0.f}, s1 = {0.f, 0.f, 0.f, 0.f};
#pragma unroll
        for (int c = 0; c < NC_GEMM; ++c) {
            const float* pr = gpart + ((long)c * N_TOK + r0 + row) * 128 + c0;
            float4 a = *(const float4*)(pr);
            float4 b = *(const float4*)(pr + 4);
            s0.x += a.x; s0.y += a.y; s0.z += a.z; s0.w += a.w;
            s1.x += b.x; s1.y += b.y; s1.z += b.z; s1.w += b.w;
        }
        const float* xr = x + (long)(r0 + row) * 128 + c0;
        v[0] = s0.x + bo[c0 + 0] + xr[0];
        v[1] = s0.y + bo[c0 + 1] + xr[1];
        v[2] = s0.z + bo[c0 + 2] + xr[2];
        v[3] = s0.w + bo[c0 + 3] + xr[3];
        v[4] = s1.x + bo[c0 + 4] + xr[4];
        v[5] = s1.y + bo[c0 + 5] + xr[5];
        v[6] = s1.z + bo[c0 + 6] + xr[6];
        v[7] = s1.w + bo[c0 + 7] + xr[7];
        float s = 0.f;
#pragma unroll
        for (int jj = 0; jj < 8; ++jj) s += v[jj];
#pragma unroll
        for (int off = 1; off < 16; off <<= 1) s += __shfl_xor(s, off);
        float mean = s * (1.0f / 128.0f);
        float ss = 0.f;
#pragma unroll
        for (int jj = 0; jj < 8; ++jj) { float d = v[jj] - mean; ss += d * d; }
#pragma unroll
        for (int off = 1; off < 16; off <<= 1) ss += __shfl_xor(ss, off);
        float rstd = rsqrtf(ss * (1.0f / 128.0f) + 1e-5f);
        union { bf16x8 vec; ushort us[8]; } pk8;
#pragma unroll
        for (int jj = 0; jj < 8; ++jj) {
            float y = (v[jj] - mean) * rstd * g1[c0 + jj] + lb1[c0 + jj];
            x1f[row][c0 + jj] = y;
            pk8.us[jj] = f2bf(y);
        }
        *(bf16x8*)(&x1b[row][c0 ^ ((row & 7) * 8)]) = pk8.vec;
    }
    __syncthreads();
    // phase 1: h = relu(x1b @ W1T^T + b1)  (wave w -> cols w*64..w*64+63)
    {
        f32x4 a1[4] = {};
#pragma unroll
        for (int ks = 0; ks < 4; ++ks) {
            bf16x8 a = *(const bf16x8*)(&x1b[fr][(ks * 32 + kg * 8) ^ ((fr & 7) * 8)]);
#pragma unroll
            for (int t = 0; t < 4; ++t) {
                bf16x8 b = *(const bf16x8*)(W1T + (long)(w * 64 + t * 16 + fr) * 128 + ks * 32 + kg * 8);
                a1[t] = __builtin_amdgcn_mfma_f32_16x16x32_bf16(a, b, a1[t], 0, 0, 0);
            }
        }
#pragma unroll
        for (int t = 0; t < 4; ++t) {
            int col = w * 64 + t * 16 + fr;
            float bs = b1[col];
#pragma unroll
            for (int r = 0; r < 4; ++r) {
                int rr = kg * 4 + r;
                hbuf[rr][col ^ ((rr & 7) * 8)] = f2bf(fmaxf(a1[t][r] + bs, 0.f));
            }
        }
    }
    __syncthreads();
    // phase 2: o = h @ W2T^T + b2 + x1  (wave w -> cols w*32..w*32+31)
    {
        f32x4 a2[2] = {};
#pragma unroll
        for (int ks = 0; ks < 8; ++ks) {
            bf16x8 a = *(const bf16x8*)(&hbuf[fr][(ks * 32 + kg * 8) ^ ((fr & 7) * 8)]);
#pragma unroll
            for (int t = 0; t < 2; ++t) {
                bf16x8 b = *(const bf16x8*)(W2T + (long)(w * 32 + t * 16 + fr) * 256 + ks * 32 + kg * 8);
                a2[t] = __builtin_amdgcn_mfma_f32_16x16x32_bf16(a, b, a2[t], 0, 0, 0);
            }
        }
#pragma unroll
        for (int t = 0; t < 2; ++t) {
            int col = w * 32 + t * 16 + fr;
            float bs = b2[col];
#pragma unroll
            for (int r = 0; r < 4; ++r) {
                int rr = kg * 4 + r;
                otile[rr][col] = a2[t][r] + bs + x1f[rr][col];
            }
        }
    }
    __syncthreads();
    // phase 2b: LN2 -> out fp32
    {
        float v[8];
        float s = 0.f;
#pragma unroll
        for (int jj = 0; jj < 8; ++jj) { v[jj] = otile[row][c0 + jj]; s += v[jj]; }
#pragma unroll
        for (int off = 1; off < 16; off <<= 1) s += __shfl_xor(s, off);
        float mean = s * (1.0f / 128.0f);
        float ss = 0.f;
#pragma unroll
        for (int jj = 0; jj < 8; ++jj) { float d = v[jj] - mean; ss += d * d; }
#pragma unroll
        for (int off = 1; off < 16; off <<= 1) ss += __shfl_xor(ss, off);
        float rstd = rsqrtf(ss * (1.0f / 128.0f) + 1e-5f);
#pragma unroll
        for (int jj = 0; jj < 8; ++jj) {
            float y = (v[jj] - mean) * rstd * g2[c0 + jj] + lb2[c0 + jj];
            out[(long)(r0 + row) * 128 + c0 + jj] = y;
        }
    }
}

extern "C" void kernel_launch(void* const* d_in, const int* in_sizes, int n_in,
                              void* d_out, int out_size, void* d_ws, size_t ws_size,
                              hipStream_t stream) {
    const float* x     = (const float*)d_in[0];
    const float* rpe   = (const float*)d_in[1];
    const float* Wq    = (const float*)d_in[2];
    const float* bq    = (const float*)d_in[3];
    const float* Wk    = (const float*)d_in[4];
    const float* bk    = (const float*)d_in[5];
    const float* Wv    = (const float*)d_in[6];
    const float* bv    = (const float*)d_in[7];
    const float* rpe_w = (const float*)d_in[8];
    const float* rpe_b = (const float*)d_in[9];
    const float* Wo    = (const float*)d_in[10];
    const float* bo    = (const float*)d_in[11];
    const float* W1    = (const float*)d_in[12];
    const float* b1    = (const float*)d_in[13];
    const float* W2    = (const float*)d_in[14];
    const float* b2    = (const float*)d_in[15];
    const float* g1    = (const float*)d_in[16];
    const float* lb1   = (const float*)d_in[17];
    const float* g2    = (const float*)d_in[18];
    const float* lb2   = (const float*)d_in[19];

    char* wp = (char*)d_ws;
    auto alloc = [&](size_t sz) { char* p = wp; wp += (sz + 255) & ~(size_t)255; return p; };
    ushort* xb    = (ushort*)alloc((size_t)4096 * 128 * 2);
    ushort* WqT   = (ushort*)alloc((size_t)4 * 64 * 128 * 2);
    ushort* WkT   = (ushort*)alloc((size_t)4 * 64 * 128 * 2);
    ushort* WvT   = (ushort*)alloc((size_t)4 * 64 * 128 * 2);
    ushort* WoT   = (ushort*)alloc((size_t)128 * 256 * 2);
    ushort* W1T   = (ushort*)alloc((size_t)256 * 128 * 2);
    ushort* W2T   = (ushort*)alloc((size_t)128 * 256 * 2);
    ushort* qb    = (ushort*)alloc((size_t)4 * 4096 * 64 * 2);
    ushort* kbuf  = (ushort*)alloc((size_t)4 * 4096 * 64 * 2);
    ushort* vT    = (ushort*)alloc((size_t)4 * 64 * 4096 * 2);
    ushort* PTb   = (ushort*)alloc((size_t)128 * 4096 * 2);
    ushort* opart = (ushort*)alloc((size_t)NC_ATT * 4 * 4096 * 64 * 2);
    float*  mlprt = (float*)alloc((size_t)NC_ATT * 4 * 4096 * 2 * 4);
    float*  gpart = (float*)alloc((size_t)NC_GEMM * 4096 * 128 * 4);

    prep_all<<<1280, 256, 0, stream>>>(x, Wq, Wk, Wv, Wo, W1, W2,
                                       xb, WqT, WkT, WvT, WoT, W1T, W2T);
    qkv_proj<<<dim3(64, 12), 256, 0, stream>>>(xb, WqT, WkT, WvT, bq, bk, bv, qb, kbuf, vT);
    attn_flash2<<<dim3(64, 4, NC_ATT), 256, 0, stream>>>(qb, kbuf, vT, opart, mlprt);
    combine_wo<<<256, 256, 0, stream>>>(opart, mlprt, WoT, PTb);
    gemm_big_fused<<<dim3(64, NC_GEMM), 512, 0, stream>>>(rpe, rpe_w, rpe_b, PTb, gpart);
    megatail<<<256, 256, 0, stream>>>(gpart, bo, x, g1, lb1, W1T, b1, W2T, b2,
                                      g2, lb2, (float*)d_out);
}